// Round 12
// baseline (1125.873 us; speedup 1.0000x reference)
//
#include <hip/hip_runtime.h>

// LightGCN conv via exact 2-level counting sort + per-row register accumulate.
// Per side (sequential, shares buffers):
//   count1 -> exscan1 -> p1 (1024-row L1 buckets, SoA meta/bf16-val out)
//   rowsort (one block per ~12K-pair chunk: registers + LDS hist + block scan
//            -> exact rowptr; 8 group passes through LDS stage -> CONTIGUOUS
//            writeback into the chunk's own span; chunk-major final layout)
//   acc    (one wave per row; CPB short segments via rowptr; 2 dims/lane so
//           one gather serves 2 edges; cross-half merge via shfl_xor(32))
// R12: R11's p2 had 9x write amplification (535MB vs 60MB: 12-25-pair scatter
// runs' dirty lines evicted by streaming reads). Chunk-local sort makes all
// sort writes sequential and deletes count2/scan2 entirely.

constexpr int DIM    = 64;
constexpr int L1BITS = 10;
constexpr int L1SZ   = 1 << L1BITS;       // rows per L1 bucket
constexpr int SHIFT  = 17;                // bits for neighbor id
constexpr unsigned NMASK = (1u << SHIFT) - 1;
constexpr int C1     = 8192;              // edges per p1 block
constexpr int K1CAP  = 128;               // max L1 buckets per side
constexpr int RSTH   = 1024;              // rowsort threads
constexpr int KMAX   = 14;                // register pairs per rowsort thread
constexpr int CAPC   = RSTH * KMAX;       // 14336 max pairs per chunk
constexpr int GROUPS = 8;                 // group passes (128 rows each)
constexpr int GRS    = L1SZ / GROUPS;     // 128
constexpr int SCAP   = 8192;              // LDS stage capacity (48 KB)
constexpr int CPBMAX = 24;

__device__ __forceinline__ ushort f2bf(unsigned u) {
    return (ushort)((u + 0x7FFFu + ((u >> 16) & 1u)) >> 16);
}
__device__ __forceinline__ float bf2f(ushort b) {
    return __uint_as_float((unsigned)b << 16);
}

// ---------------- fallback (round-1) atomic kernel ----------------
__global__ void lightgcn_scatter_atomic(const float* __restrict__ user_emb,
                                        const float* __restrict__ item_emb,
                                        const int* __restrict__ rows,
                                        const int* __restrict__ cols,
                                        const float* __restrict__ vals,
                                        float* __restrict__ user_out,
                                        float* __restrict__ item_out,
                                        int nnz) {
    const int lane   = threadIdx.x & 63;
    const int wave   = (blockIdx.x * blockDim.x + threadIdx.x) >> 6;
    const int nwaves = (gridDim.x * blockDim.x) >> 6;
    for (int e = wave; e < nnz; e += nwaves) {
        const int r = rows[e];
        const int c = cols[e];
        const float v = vals[e];
        atomicAdd(&user_out[(size_t)r * DIM + lane], v * item_emb[(size_t)c * DIM + lane]);
        atomicAdd(&item_out[(size_t)c * DIM + lane], v * user_emb[(size_t)r * DIM + lane]);
    }
}

// ---------------- bf16 table conversion (RNE) ----------------
__global__ void to_bf16(const float* __restrict__ a, int n, ushort* __restrict__ o) {
    int i = blockIdx.x * blockDim.x + threadIdx.x;
    const int s = gridDim.x * blockDim.x;
    for (; i < n; i += s) o[i] = f2bf(__float_as_uint(a[i]));
}

// ---------------- count1: L1-bucket histogram (int4 loads) ----------------
__global__ __launch_bounds__(256)
void count1_kernel(const int* __restrict__ dest, int nnz, int K1,
                   int* __restrict__ counts1) {
    __shared__ int h[K1CAP * 4];
    const int tid = threadIdx.x;
    for (int t = tid; t < K1 * 4; t += 256) h[t] = 0;
    __syncthreads();
    const int rr = tid & 3;
    const int nq = nnz >> 2;
    const int4* d4 = (const int4*)dest;
    for (int i = blockIdx.x * 256 + tid; i < nq; i += gridDim.x * 256) {
        const int4 d = d4[i];
        atomicAdd(&h[((d.x >> L1BITS) << 2) | rr], 1);
        atomicAdd(&h[((d.y >> L1BITS) << 2) | rr], 1);
        atomicAdd(&h[((d.z >> L1BITS) << 2) | rr], 1);
        atomicAdd(&h[((d.w >> L1BITS) << 2) | rr], 1);
    }
    for (int i = (nq << 2) + blockIdx.x * 256 + tid; i < nnz; i += gridDim.x * 256)
        atomicAdd(&h[((dest[i] >> L1BITS) << 2) | rr], 1);
    __syncthreads();
    for (int b = tid; b < K1; b += 256) {
        const int c = h[b*4] + h[b*4+1] + h[b*4+2] + h[b*4+3];
        if (c) atomicAdd(&counts1[b], c);
    }
}

// ---------------- exscan over K1 buckets (1 block) ----------------
__global__ __launch_bounds__(1024)
void exscan_block(const int* __restrict__ src, int n,
                  int* __restrict__ base, int* __restrict__ cursor) {
    __shared__ int s[1024];
    const int tid = threadIdx.x;
    const int len = (n + 1023) >> 10;
    const int lo = min(tid * len, n);
    const int hi = min(lo + len, n);
    int sum = 0;
    for (int i = lo; i < hi; ++i) sum += src[i];
    s[tid] = sum;
    __syncthreads();
    for (int off = 1; off < 1024; off <<= 1) {
        const int t = (tid >= off) ? s[tid - off] : 0;
        __syncthreads();
        s[tid] += t;
        __syncthreads();
    }
    int run = tid ? s[tid - 1] : 0;
    for (int i = lo; i < hi; ++i) {
        const int c = src[i];
        base[i] = run; cursor[i] = run;
        run += c;
    }
}

// ---------------- p1: edges -> L1-bucket-grouped SoA (meta, bf16 val) --------
__global__ __launch_bounds__(256)
void p1_kernel(const int* __restrict__ dest, const int* __restrict__ nbr,
               const float* __restrict__ vals, int nnz, int K1,
               int* __restrict__ cursor1,
               unsigned* __restrict__ meta1, ushort* __restrict__ val1) {
    __shared__ int h[K1CAP * 4];
    __shared__ int gd[K1CAP];
    __shared__ int lc[K1CAP];
    const int tid = threadIdx.x;
    const int e0 = blockIdx.x * C1;
    const int e1 = min(e0 + C1, nnz);
    for (int t = tid; t < K1 * 4; t += 256) h[t] = 0;
    for (int t = tid; t < K1; t += 256) lc[t] = 0;
    __syncthreads();
    const int rr = tid & 3;
    const int nfull = (e1 - e0) & ~3;
    const int4* d4 = (const int4*)(dest + e0);
    for (int q = tid; q < (nfull >> 2); q += 256) {
        const int4 d = d4[q];
        atomicAdd(&h[((d.x >> L1BITS) << 2) | rr], 1);
        atomicAdd(&h[((d.y >> L1BITS) << 2) | rr], 1);
        atomicAdd(&h[((d.z >> L1BITS) << 2) | rr], 1);
        atomicAdd(&h[((d.w >> L1BITS) << 2) | rr], 1);
    }
    for (int e = e0 + nfull + tid; e < e1; e += 256)
        atomicAdd(&h[((dest[e] >> L1BITS) << 2) | rr], 1);
    __syncthreads();
    for (int b = tid; b < K1; b += 256) {
        const int c = h[b*4] + h[b*4+1] + h[b*4+2] + h[b*4+3];
        gd[b] = c ? atomicAdd(&cursor1[b], c) : 0;
    }
    __syncthreads();
    const int4*   n4 = (const int4*)(nbr + e0);
    const float4* v4 = (const float4*)(vals + e0);
    for (int q = tid; q < (nfull >> 2); q += 256) {
        const int4 d = d4[q];
        const int4 nb = n4[q];
        const float4 vv = v4[q];
        {   const int b = d.x >> L1BITS;
            const int s = gd[b] + atomicAdd(&lc[b], 1);
            meta1[s] = ((unsigned)(d.x & (L1SZ-1)) << SHIFT) | (unsigned)nb.x;
            val1[s] = f2bf(__float_as_uint(vv.x)); }
        {   const int b = d.y >> L1BITS;
            const int s = gd[b] + atomicAdd(&lc[b], 1);
            meta1[s] = ((unsigned)(d.y & (L1SZ-1)) << SHIFT) | (unsigned)nb.y;
            val1[s] = f2bf(__float_as_uint(vv.y)); }
        {   const int b = d.z >> L1BITS;
            const int s = gd[b] + atomicAdd(&lc[b], 1);
            meta1[s] = ((unsigned)(d.z & (L1SZ-1)) << SHIFT) | (unsigned)nb.z;
            val1[s] = f2bf(__float_as_uint(vv.z)); }
        {   const int b = d.w >> L1BITS;
            const int s = gd[b] + atomicAdd(&lc[b], 1);
            meta1[s] = ((unsigned)(d.w & (L1SZ-1)) << SHIFT) | (unsigned)nb.w;
            val1[s] = f2bf(__float_as_uint(vv.w)); }
    }
    for (int e = e0 + nfull + tid; e < e1; e += 256) {
        const int d = dest[e];
        const int b = d >> L1BITS;
        const int s = gd[b] + atomicAdd(&lc[b], 1);
        meta1[s] = ((unsigned)(d & (L1SZ-1)) << SHIFT) | (unsigned)nbr[e];
        val1[s] = f2bf(__float_as_uint(vals[e]));
    }
}

// ---------------- rowsort: local chunk sort, contiguous writes ----------------
// Block (B,j): slice [s0,s1) of bucket B held in registers; LDS hist of 1024
// rows; block scan -> exact rowptr (+sentinel); 8 group passes scatter via
// LDS stage; sequential writeback into the same span (out-of-place buffers).
__global__ __launch_bounds__(RSTH)
void rowsort_kernel(const unsigned* __restrict__ meta1,
                    const ushort* __restrict__ val1,
                    const int* __restrict__ bases1,
                    const int* __restrict__ counts1,
                    int CPB, int* __restrict__ rowptr, int* __restrict__ chunk_bad,
                    unsigned* __restrict__ meta2, ushort* __restrict__ val2) {
    __shared__ unsigned smeta[SCAP];   // 32 KiB
    __shared__ ushort   sval[SCAP];    // 16 KiB
    __shared__ int      ssum[RSTH];    // 4 KiB (inclusive row-count scan)
    __shared__ int      cur[L1SZ];     // 4 KiB (hist, then cursors)
    __shared__ int      gbad;
    const int cid = blockIdx.x;
    const int B = cid / CPB, j = cid - B * CPB;
    const int tid = threadIdx.x;
    const int nb  = counts1[B];
    const int bst = bases1[B];
    const int csz = (nb + CPB - 1) / CPB;
    const int s0 = min(bst + j * csz, bst + nb);
    const int s1 = min(s0 + csz, bst + nb);
    const int n = s1 - s0;
    int* rp = rowptr + (size_t)cid * (L1SZ + 1);

    if (n > CAPC) {   // >30 sigma; correct slow fallback (acc filters)
        for (int i = tid; i < n; i += RSTH) {
            meta2[s0 + i] = meta1[s0 + i];
            val2[s0 + i]  = val1[s0 + i];
        }
        rp[tid] = s0;
        if (tid == 0) { rp[L1SZ] = s1; chunk_bad[cid] = 1; }
        return;
    }

    cur[tid] = 0;
    if (tid == 0) gbad = 0;
    __syncthreads();

    unsigned mv[KMAX];
    ushort   vv[KMAX];
    #pragma unroll
    for (int k = 0; k < KMAX; ++k) {
        const int i = tid + k * RSTH;
        if (i < n) {
            mv[k] = __builtin_nontemporal_load(&meta1[s0 + i]);
            vv[k] = __builtin_nontemporal_load(&val1[s0 + i]);
            atomicAdd(&cur[mv[k] >> SHIFT], 1);
        }
    }
    __syncthreads();
    ssum[tid] = cur[tid];
    __syncthreads();
    for (int off = 1; off < RSTH; off <<= 1) {
        const int t = (tid >= off) ? ssum[tid - off] : 0;
        __syncthreads();
        ssum[tid] += t;
        __syncthreads();
    }
    const int excl = tid ? ssum[tid - 1] : 0;
    rp[tid] = s0 + excl;
    cur[tid] = excl;
    if (tid == 0) rp[L1SZ] = s1;
    if (tid < GROUPS) {
        const int gs = tid ? ssum[tid * GRS - 1] : 0;
        if (ssum[(tid + 1) * GRS - 1] - gs > SCAP) gbad = 1;
    }
    __syncthreads();

    if (gbad) {   // stage overflow (>100 sigma); correct fallback from regs
        #pragma unroll
        for (int k = 0; k < KMAX; ++k) {
            const int i = tid + k * RSTH;
            if (i < n) { meta2[s0 + i] = mv[k]; val2[s0 + i] = vv[k]; }
        }
        if (tid == 0) chunk_bad[cid] = 1;
        return;
    }
    if (tid == 0) chunk_bad[cid] = 0;

    for (int g = 0; g < GROUPS; ++g) {
        const int gs = g ? ssum[g * GRS - 1] : 0;
        const int ge = ssum[(g + 1) * GRS - 1];
        #pragma unroll
        for (int k = 0; k < KMAX; ++k) {
            const int i = tid + k * RSTH;
            if (i < n) {
                const int row = (int)(mv[k] >> SHIFT);
                if ((row >> 7) == g) {               // GRS = 128
                    const int slot = atomicAdd(&cur[row], 1);
                    smeta[slot - gs] = mv[k];
                    sval[slot - gs]  = vv[k];
                }
            }
        }
        __syncthreads();
        for (int i = tid; i < ge - gs; i += RSTH) {
            meta2[s0 + gs + i] = smeta[i];
            val2[s0 + gs + i]  = sval[i];
        }
        __syncthreads();
    }
}

// ---------------- acc: one wave per row, CPB segments, 2 dims/lane -----------
__global__ __launch_bounds__(256)
void acc_kernel(const ushort* __restrict__ tbl,
                const unsigned* __restrict__ meta2,
                const ushort* __restrict__ val2,
                const int* __restrict__ rowptr,
                const int* __restrict__ chunk_bad,
                int CPB, int nrows, float* __restrict__ out) {
    const int lane = threadIdx.x & 63;
    const int half = lane >> 5;
    const int li   = lane & 31;
    const int r = (int)((blockIdx.x * blockDim.x + threadIdx.x) >> 6);
    const int B = r >> L1BITS;
    const int rlow = r & (L1SZ - 1);
    float ax = 0.f, ay = 0.f;
    #define STEP(EI) {                                                        \
        const unsigned m_ = meta2[EI];                                        \
        const float v_ = bf2f(val2[EI]);                                      \
        const ushort2 g_ = *(const ushort2*)(tbl + (size_t)(m_ & NMASK) * DIM + 2*li); \
        ax = fmaf(v_, bf2f(g_.x), ax);                                        \
        ay = fmaf(v_, bf2f(g_.y), ay); }
    for (int j = 0; j < CPB; ++j) {
        const int cid = B * CPB + j;
        const int* rp = rowptr + (size_t)cid * (L1SZ + 1);
        if (__builtin_expect(chunk_bad[cid] != 0, 0)) {
            const int cs = rp[0], ce = rp[L1SZ];
            for (int e = cs + half; e < ce; e += 2) {
                const unsigned m_ = meta2[e];
                if ((int)(m_ >> SHIFT) == rlow) {
                    const float v_ = bf2f(val2[e]);
                    const ushort2 g_ = *(const ushort2*)(tbl + (size_t)(m_ & NMASK) * DIM + 2*li);
                    ax = fmaf(v_, bf2f(g_.x), ax);
                    ay = fmaf(v_, bf2f(g_.y), ay);
                }
            }
        } else {
            const int st = rp[rlow];
            const int en = rp[rlow + 1];
            int e = st;
            for (; e + 4 <= en; e += 4) { STEP(e + half); STEP(e + 2 + half); }
            for (; e + 2 <= en; e += 2) STEP(e + half);
            if (e < en && half == 0) STEP(e);
        }
    }
    #undef STEP
    ax += __shfl_xor(ax, 32);
    ay += __shfl_xor(ay, 32);
    if (half == 0 && r < nrows)
        *(float2*)(out + (size_t)r * DIM + 2*li) = make_float2(ax, ay);
}

extern "C" void kernel_launch(void* const* d_in, const int* in_sizes, int n_in,
                              void* d_out, int out_size, void* d_ws, size_t ws_size,
                              hipStream_t stream) {
    const float* user_emb = (const float*)d_in[0];
    const float* item_emb = (const float*)d_in[1];
    const int*   rows     = (const int*)d_in[2];
    const int*   cols     = (const int*)d_in[3];
    const float* vals     = (const float*)d_in[4];

    const int nnz     = in_sizes[2];
    const int n_users = in_sizes[0] / DIM;
    const int n_items = in_sizes[1] / DIM;

    float* user_out = (float*)d_out;
    float* item_out = (float*)d_out + (size_t)in_sizes[0];

    // ---- workspace layout ----
    size_t oi = 0;
    const size_t counts1_o  = oi; oi += K1CAP;
    const size_t bases1_o   = oi; oi += K1CAP;
    const size_t cursor1_o  = oi; oi += K1CAP;
    const size_t cbad_o     = oi; oi += (size_t)K1CAP * CPBMAX;
    const size_t rowptr_o   = oi; oi += (size_t)K1CAP * CPBMAX * (L1SZ + 1);
    const size_t meta_bytes = oi * sizeof(int);
    const size_t tbl_off     = (meta_bytes + 255) & ~(size_t)255;
    const size_t tblu_bytes  = (size_t)n_users * DIM * sizeof(ushort);
    const size_t tbli_bytes  = (size_t)n_items * DIM * sizeof(ushort);
    const size_t meta1_off   = (tbl_off + tblu_bytes + tbli_bytes + 255) & ~(size_t)255;
    const size_t val1_off    = meta1_off + (((size_t)nnz * 4 + 255) & ~(size_t)255);
    const size_t meta2_off   = val1_off + (((size_t)nnz * 2 + 255) & ~(size_t)255);
    const size_t val2_off    = meta2_off + (((size_t)nnz * 4 + 255) & ~(size_t)255);
    const size_t need        = val2_off + (size_t)nnz * sizeof(ushort);

    if (n_users > (1 << SHIFT) || n_items > (1 << SHIFT) ||
        n_users > K1CAP * L1SZ || n_items > K1CAP * L1SZ || ws_size < need) {
        hipMemsetAsync(d_out, 0, (size_t)out_size * sizeof(float), stream);
        lightgcn_scatter_atomic<<<2048, 256, 0, stream>>>(user_emb, item_emb, rows,
                                                          cols, vals, user_out,
                                                          item_out, nnz);
        return;
    }

    int* wsi       = (int*)d_ws;
    int* counts1   = wsi + counts1_o;
    int* bases1    = wsi + bases1_o;
    int* cursor1   = wsi + cursor1_o;
    int* chunk_bad = wsi + cbad_o;
    int* rowptr    = wsi + rowptr_o;
    ushort* tblu   = (ushort*)((char*)d_ws + tbl_off);
    ushort* tbli   = tblu + (size_t)n_users * DIM;
    unsigned* meta1 = (unsigned*)((char*)d_ws + meta1_off);
    ushort*   val1  = (ushort*)((char*)d_ws + val1_off);
    unsigned* meta2 = (unsigned*)((char*)d_ws + meta2_off);
    ushort*   val2  = (ushort*)((char*)d_ws + val2_off);

    to_bf16<<<2048, 256, 0, stream>>>(user_emb, n_users * DIM, tblu);
    to_bf16<<<2048, 256, 0, stream>>>(item_emb, n_items * DIM, tbli);

    const int p1_grid = (nnz + C1 - 1) / C1;

    struct Side { const int* dest; const int* nbr; int nrows; const ushort* tbl; float* out; };
    const Side sides[2] = {
        { cols, rows, n_items, tblu, item_out },   // item side gathers USER rows
        { rows, cols, n_users, tbli, user_out },   // user side gathers ITEM rows
    };

    for (int s = 0; s < 2; ++s) {
        const Side& S = sides[s];
        const int K1 = (S.nrows + L1SZ - 1) >> L1BITS;
        const long long meanb = (long long)nnz / K1;
        int CPB = (int)((meanb + 12287) / 12288);
        if (CPB < 1) CPB = 1;
        if (CPB > CPBMAX) CPB = CPBMAX;
        hipMemsetAsync(counts1, 0, (size_t)K1 * sizeof(int), stream);
        count1_kernel<<<1024, 256, 0, stream>>>(S.dest, nnz, K1, counts1);
        exscan_block<<<1, 1024, 0, stream>>>(counts1, K1, bases1, cursor1);
        p1_kernel<<<p1_grid, 256, 0, stream>>>(S.dest, S.nbr, vals, nnz, K1,
                                               cursor1, meta1, val1);
        rowsort_kernel<<<K1 * CPB, RSTH, 0, stream>>>(meta1, val1, bases1, counts1,
                                                      CPB, rowptr, chunk_bad,
                                                      meta2, val2);
        const int acc_grid = K1 * (L1SZ / 4);   // 4 rows (waves) per block
        acc_kernel<<<acc_grid, 256, 0, stream>>>(S.tbl, meta2, val2, rowptr,
                                                 chunk_bad, CPB, S.nrows, S.out);
    }
}

// Round 13
// 829.324 us; speedup vs baseline: 1.3576x; 1.3576x over previous
//
#include <hip/hip_runtime.h>

// LightGCN conv via exact 2-level counting sort + per-row register accumulate.
// Per side (sequential, shares buffers):
//   count1 -> exscan1 -> p1 (256-row L1 buckets, SoA meta/bf16-val out)
//   rowsort (one block per ~10K-pair chunk: registers + LDS hist + 256-scan
//            -> exact rowptr; 2 group passes through LDS stage -> contiguous
//            writeback; chunk-major layout, CPB=3..5 segments per row)
//   acc<CPB> (one wave per row; hoisted segment bounds in registers;
//            quarter-wave ushort4 gathers = 4 edges per VMEM instruction)
// R13: R12's acc regressed 254->369 from CPB=17 x 12-pair segments (latency
// bound). L1SZ 1024->256 cuts segments to 3-5 x ~45 pairs; bounds hoisting +
// 4-edge gathers restore memory-level parallelism.

constexpr int DIM    = 64;
constexpr int L1BITS = 8;
constexpr int L1SZ   = 1 << L1BITS;       // rows per L1 bucket
constexpr int SHIFT  = 17;                // bits for neighbor id
constexpr unsigned NMASK = (1u << SHIFT) - 1;
constexpr int C1     = 16384;             // edges per p1 block
constexpr int P1T    = 512;               // p1 threads
constexpr int K1CAP  = 512;               // max L1 buckets per side
constexpr int RSTH   = 1024;              // rowsort threads
constexpr int KMAX   = 14;                // register pairs per rowsort thread
constexpr int CAPC   = RSTH * KMAX;       // 14336 max pairs per chunk
constexpr int GROUPS = 2;                 // group passes (128 rows each)
constexpr int GRS    = L1SZ / GROUPS;     // 128
constexpr int SCAP   = 8192;              // LDS stage capacity (48 KB)
constexpr int CPBMAX = 8;

__device__ __forceinline__ ushort f2bf(unsigned u) {
    return (ushort)((u + 0x7FFFu + ((u >> 16) & 1u)) >> 16);
}
__device__ __forceinline__ float bf2f(ushort b) {
    return __uint_as_float((unsigned)b << 16);
}

// ---------------- fallback (round-1) atomic kernel ----------------
__global__ void lightgcn_scatter_atomic(const float* __restrict__ user_emb,
                                        const float* __restrict__ item_emb,
                                        const int* __restrict__ rows,
                                        const int* __restrict__ cols,
                                        const float* __restrict__ vals,
                                        float* __restrict__ user_out,
                                        float* __restrict__ item_out,
                                        int nnz) {
    const int lane   = threadIdx.x & 63;
    const int wave   = (blockIdx.x * blockDim.x + threadIdx.x) >> 6;
    const int nwaves = (gridDim.x * blockDim.x) >> 6;
    for (int e = wave; e < nnz; e += nwaves) {
        const int r = rows[e];
        const int c = cols[e];
        const float v = vals[e];
        atomicAdd(&user_out[(size_t)r * DIM + lane], v * item_emb[(size_t)c * DIM + lane]);
        atomicAdd(&item_out[(size_t)c * DIM + lane], v * user_emb[(size_t)r * DIM + lane]);
    }
}

// ---------------- bf16 table conversion (RNE) ----------------
__global__ void to_bf16(const float* __restrict__ a, int n, ushort* __restrict__ o) {
    int i = blockIdx.x * blockDim.x + threadIdx.x;
    const int s = gridDim.x * blockDim.x;
    for (; i < n; i += s) o[i] = f2bf(__float_as_uint(a[i]));
}

// ---------------- count1: L1-bucket histogram (int4 loads) ----------------
__global__ __launch_bounds__(256)
void count1_kernel(const int* __restrict__ dest, int nnz, int K1,
                   int* __restrict__ counts1) {
    __shared__ int h[K1CAP * 4];
    const int tid = threadIdx.x;
    for (int t = tid; t < K1 * 4; t += 256) h[t] = 0;
    __syncthreads();
    const int rr = tid & 3;
    const int nq = nnz >> 2;
    const int4* d4 = (const int4*)dest;
    for (int i = blockIdx.x * 256 + tid; i < nq; i += gridDim.x * 256) {
        const int4 d = d4[i];
        atomicAdd(&h[((d.x >> L1BITS) << 2) | rr], 1);
        atomicAdd(&h[((d.y >> L1BITS) << 2) | rr], 1);
        atomicAdd(&h[((d.z >> L1BITS) << 2) | rr], 1);
        atomicAdd(&h[((d.w >> L1BITS) << 2) | rr], 1);
    }
    for (int i = (nq << 2) + blockIdx.x * 256 + tid; i < nnz; i += gridDim.x * 256)
        atomicAdd(&h[((dest[i] >> L1BITS) << 2) | rr], 1);
    __syncthreads();
    for (int b = tid; b < K1; b += 256) {
        const int c = h[b*4] + h[b*4+1] + h[b*4+2] + h[b*4+3];
        if (c) atomicAdd(&counts1[b], c);
    }
}

// ---------------- exscan over K1 buckets (1 block) ----------------
__global__ __launch_bounds__(1024)
void exscan_block(const int* __restrict__ src, int n,
                  int* __restrict__ base, int* __restrict__ cursor) {
    __shared__ int s[1024];
    const int tid = threadIdx.x;
    const int len = (n + 1023) >> 10;
    const int lo = min(tid * len, n);
    const int hi = min(lo + len, n);
    int sum = 0;
    for (int i = lo; i < hi; ++i) sum += src[i];
    s[tid] = sum;
    __syncthreads();
    for (int off = 1; off < 1024; off <<= 1) {
        const int t = (tid >= off) ? s[tid - off] : 0;
        __syncthreads();
        s[tid] += t;
        __syncthreads();
    }
    int run = tid ? s[tid - 1] : 0;
    for (int i = lo; i < hi; ++i) {
        const int c = src[i];
        base[i] = run; cursor[i] = run;
        run += c;
    }
}

// ---------------- p1: edges -> L1-bucket-grouped SoA (meta, bf16 val) --------
__global__ __launch_bounds__(P1T)
void p1_kernel(const int* __restrict__ dest, const int* __restrict__ nbr,
               const float* __restrict__ vals, int nnz, int K1,
               int* __restrict__ cursor1,
               unsigned* __restrict__ meta1, ushort* __restrict__ val1) {
    __shared__ int h[K1CAP * 4];
    __shared__ int gd[K1CAP];
    __shared__ int lc[K1CAP];
    const int tid = threadIdx.x;
    const int e0 = blockIdx.x * C1;
    const int e1 = min(e0 + C1, nnz);
    for (int t = tid; t < K1 * 4; t += P1T) h[t] = 0;
    for (int t = tid; t < K1; t += P1T) lc[t] = 0;
    __syncthreads();
    const int rr = tid & 3;
    const int nfull = (e1 - e0) & ~3;
    const int4* d4 = (const int4*)(dest + e0);
    for (int q = tid; q < (nfull >> 2); q += P1T) {
        const int4 d = d4[q];
        atomicAdd(&h[((d.x >> L1BITS) << 2) | rr], 1);
        atomicAdd(&h[((d.y >> L1BITS) << 2) | rr], 1);
        atomicAdd(&h[((d.z >> L1BITS) << 2) | rr], 1);
        atomicAdd(&h[((d.w >> L1BITS) << 2) | rr], 1);
    }
    for (int e = e0 + nfull + tid; e < e1; e += P1T)
        atomicAdd(&h[((dest[e] >> L1BITS) << 2) | rr], 1);
    __syncthreads();
    for (int b = tid; b < K1; b += P1T) {
        const int c = h[b*4] + h[b*4+1] + h[b*4+2] + h[b*4+3];
        gd[b] = c ? atomicAdd(&cursor1[b], c) : 0;
    }
    __syncthreads();
    const int4*   n4 = (const int4*)(nbr + e0);
    const float4* v4 = (const float4*)(vals + e0);
    for (int q = tid; q < (nfull >> 2); q += P1T) {
        const int4 d = d4[q];
        const int4 nb = n4[q];
        const float4 vv = v4[q];
        {   const int b = d.x >> L1BITS;
            const int s = gd[b] + atomicAdd(&lc[b], 1);
            meta1[s] = ((unsigned)(d.x & (L1SZ-1)) << SHIFT) | (unsigned)nb.x;
            val1[s] = f2bf(__float_as_uint(vv.x)); }
        {   const int b = d.y >> L1BITS;
            const int s = gd[b] + atomicAdd(&lc[b], 1);
            meta1[s] = ((unsigned)(d.y & (L1SZ-1)) << SHIFT) | (unsigned)nb.y;
            val1[s] = f2bf(__float_as_uint(vv.y)); }
        {   const int b = d.z >> L1BITS;
            const int s = gd[b] + atomicAdd(&lc[b], 1);
            meta1[s] = ((unsigned)(d.z & (L1SZ-1)) << SHIFT) | (unsigned)nb.z;
            val1[s] = f2bf(__float_as_uint(vv.z)); }
        {   const int b = d.w >> L1BITS;
            const int s = gd[b] + atomicAdd(&lc[b], 1);
            meta1[s] = ((unsigned)(d.w & (L1SZ-1)) << SHIFT) | (unsigned)nb.w;
            val1[s] = f2bf(__float_as_uint(vv.w)); }
    }
    for (int e = e0 + nfull + tid; e < e1; e += P1T) {
        const int d = dest[e];
        const int b = d >> L1BITS;
        const int s = gd[b] + atomicAdd(&lc[b], 1);
        meta1[s] = ((unsigned)(d & (L1SZ-1)) << SHIFT) | (unsigned)nbr[e];
        val1[s] = f2bf(__float_as_uint(vals[e]));
    }
}

// ---------------- rowsort: local chunk sort, contiguous writes ----------------
__global__ __launch_bounds__(RSTH)
void rowsort_kernel(const unsigned* __restrict__ meta1,
                    const ushort* __restrict__ val1,
                    const int* __restrict__ bases1,
                    const int* __restrict__ counts1,
                    int CPB, int* __restrict__ rowptr, int* __restrict__ chunk_bad,
                    unsigned* __restrict__ meta2, ushort* __restrict__ val2) {
    __shared__ unsigned smeta[SCAP];   // 32 KiB
    __shared__ ushort   sval[SCAP];    // 16 KiB
    __shared__ int      ssum[L1SZ];
    __shared__ int      cur[L1SZ];
    __shared__ int      gbad;
    const int cid = blockIdx.x;
    const int B = cid / CPB, j = cid - B * CPB;
    const int tid = threadIdx.x;
    const int nb  = counts1[B];
    const int bst = bases1[B];
    const int csz = (nb + CPB - 1) / CPB;
    const int s0 = min(bst + j * csz, bst + nb);
    const int s1 = min(s0 + csz, bst + nb);
    const int n = s1 - s0;
    int* rp = rowptr + (size_t)cid * (L1SZ + 1);

    if (n > CAPC) {   // far beyond sigma; correct slow fallback (acc filters)
        for (int i = tid; i < n; i += RSTH) {
            meta2[s0 + i] = meta1[s0 + i];
            val2[s0 + i]  = val1[s0 + i];
        }
        if (tid < L1SZ) rp[tid] = s0;
        if (tid == 0) { rp[L1SZ] = s1; chunk_bad[cid] = 1; }
        return;
    }

    if (tid < L1SZ) cur[tid] = 0;
    if (tid == 0) gbad = 0;
    __syncthreads();

    unsigned mv[KMAX];
    ushort   vv[KMAX];
    #pragma unroll
    for (int k = 0; k < KMAX; ++k) {
        const int i = tid + k * RSTH;
        if (i < n) {
            mv[k] = __builtin_nontemporal_load(&meta1[s0 + i]);
            vv[k] = __builtin_nontemporal_load(&val1[s0 + i]);
            atomicAdd(&cur[mv[k] >> SHIFT], 1);
        }
    }
    __syncthreads();
    if (tid < L1SZ) ssum[tid] = cur[tid];
    __syncthreads();
    for (int off = 1; off < L1SZ; off <<= 1) {
        int t = 0;
        if (tid < L1SZ && tid >= off) t = ssum[tid - off];
        __syncthreads();
        if (tid < L1SZ) ssum[tid] += t;
        __syncthreads();
    }
    if (tid < L1SZ) {
        const int excl = tid ? ssum[tid - 1] : 0;
        rp[tid] = s0 + excl;
        cur[tid] = excl;
    }
    if (tid == 0) rp[L1SZ] = s1;
    if (tid < GROUPS) {
        const int gs = tid ? ssum[tid * GRS - 1] : 0;
        if (ssum[(tid + 1) * GRS - 1] - gs > SCAP) gbad = 1;
    }
    __syncthreads();

    if (gbad) {   // stage overflow (way out on the tail); correct fallback
        #pragma unroll
        for (int k = 0; k < KMAX; ++k) {
            const int i = tid + k * RSTH;
            if (i < n) { meta2[s0 + i] = mv[k]; val2[s0 + i] = vv[k]; }
        }
        if (tid == 0) chunk_bad[cid] = 1;
        return;
    }
    if (tid == 0) chunk_bad[cid] = 0;

    for (int g = 0; g < GROUPS; ++g) {
        const int gs = g ? ssum[g * GRS - 1] : 0;
        const int ge = ssum[(g + 1) * GRS - 1];
        #pragma unroll
        for (int k = 0; k < KMAX; ++k) {
            const int i = tid + k * RSTH;
            if (i < n) {
                const int row = (int)(mv[k] >> SHIFT);
                if ((row >> 7) == g) {               // GRS = 128
                    const int slot = atomicAdd(&cur[row], 1);
                    smeta[slot - gs] = mv[k];
                    sval[slot - gs]  = vv[k];
                }
            }
        }
        __syncthreads();
        for (int i = tid; i < ge - gs; i += RSTH) {
            meta2[s0 + gs + i] = smeta[i];
            val2[s0 + gs + i]  = sval[i];
        }
        __syncthreads();
    }
}

// ---------------- acc: wave/row, hoisted bounds, quarter-wave ushort4 --------
template<int CPBT>
__global__ __launch_bounds__(256)
void acc_kernel(const ushort* __restrict__ tbl,
                const unsigned* __restrict__ meta2,
                const ushort* __restrict__ val2,
                const int* __restrict__ rowptr,
                const int* __restrict__ chunk_bad,
                int nrows, float* __restrict__ out) {
    const int lane = threadIdx.x & 63;
    const int q  = lane >> 4;     // quarter handles edge e+q
    const int li = lane & 15;     // dims 4*li .. 4*li+3
    const int r = (int)((blockIdx.x * blockDim.x + threadIdx.x) >> 6);
    const int B = r >> L1BITS;
    const int rlow = r & (L1SZ - 1);
    int stj[CPBT], enj[CPBT], cbj[CPBT];
    #pragma unroll
    for (int j = 0; j < CPBT; ++j) {
        const int cid = B * CPBT + j;
        const int* rp = rowptr + (size_t)cid * (L1SZ + 1);
        cbj[j] = chunk_bad[cid];
        stj[j] = rp[rlow];
        enj[j] = rp[rlow + 1];
    }
    float a0 = 0.f, a1 = 0.f, a2 = 0.f, a3 = 0.f;
    #define STEP(EI) { const unsigned m_ = meta2[EI];                          \
        const float v_ = bf2f(val2[EI]);                                       \
        const ushort4 g_ = *(const ushort4*)(tbl + (size_t)(m_ & NMASK) * DIM + 4*li); \
        a0 = fmaf(v_, bf2f(g_.x), a0); a1 = fmaf(v_, bf2f(g_.y), a1);          \
        a2 = fmaf(v_, bf2f(g_.z), a2); a3 = fmaf(v_, bf2f(g_.w), a3); }
    #pragma unroll
    for (int j = 0; j < CPBT; ++j) {
        if (__builtin_expect(cbj[j] != 0, 0)) {
            const int cid = B * CPBT + j;
            const int* rp = rowptr + (size_t)cid * (L1SZ + 1);
            const int cs = rp[0], ce = rp[L1SZ];
            for (int e = cs; e < ce; e += 4) {
                if (e + q < ce) {
                    const unsigned m_ = meta2[e + q];
                    if ((int)(m_ >> SHIFT) == rlow) {
                        const float v_ = bf2f(val2[e + q]);
                        const ushort4 g_ = *(const ushort4*)(tbl + (size_t)(m_ & NMASK) * DIM + 4*li);
                        a0 = fmaf(v_, bf2f(g_.x), a0); a1 = fmaf(v_, bf2f(g_.y), a1);
                        a2 = fmaf(v_, bf2f(g_.z), a2); a3 = fmaf(v_, bf2f(g_.w), a3);
                    }
                }
            }
        } else {
            const int en = enj[j];
            int e = stj[j];
            for (; e + 8 <= en; e += 8) { STEP(e + q); STEP(e + 4 + q); }
            if (e + 4 <= en) { STEP(e + q); e += 4; }
            if (e + q < en) STEP(e + q);
        }
    }
    #undef STEP
    a0 += __shfl_xor(a0, 16); a0 += __shfl_xor(a0, 32);
    a1 += __shfl_xor(a1, 16); a1 += __shfl_xor(a1, 32);
    a2 += __shfl_xor(a2, 16); a2 += __shfl_xor(a2, 32);
    a3 += __shfl_xor(a3, 16); a3 += __shfl_xor(a3, 32);
    if (lane < 16 && r < nrows)
        *(float4*)(out + (size_t)r * DIM + 4*li) = make_float4(a0, a1, a2, a3);
}

extern "C" void kernel_launch(void* const* d_in, const int* in_sizes, int n_in,
                              void* d_out, int out_size, void* d_ws, size_t ws_size,
                              hipStream_t stream) {
    const float* user_emb = (const float*)d_in[0];
    const float* item_emb = (const float*)d_in[1];
    const int*   rows     = (const int*)d_in[2];
    const int*   cols     = (const int*)d_in[3];
    const float* vals     = (const float*)d_in[4];

    const int nnz     = in_sizes[2];
    const int n_users = in_sizes[0] / DIM;
    const int n_items = in_sizes[1] / DIM;

    float* user_out = (float*)d_out;
    float* item_out = (float*)d_out + (size_t)in_sizes[0];

    // ---- workspace layout ----
    size_t oi = 0;
    const size_t counts1_o  = oi; oi += K1CAP;
    const size_t bases1_o   = oi; oi += K1CAP;
    const size_t cursor1_o  = oi; oi += K1CAP;
    const size_t cbad_o     = oi; oi += (size_t)K1CAP * CPBMAX;
    const size_t rowptr_o   = oi; oi += (size_t)K1CAP * CPBMAX * (L1SZ + 1);
    const size_t meta_bytes = oi * sizeof(int);
    const size_t tbl_off     = (meta_bytes + 255) & ~(size_t)255;
    const size_t tblu_bytes  = (size_t)n_users * DIM * sizeof(ushort);
    const size_t tbli_bytes  = (size_t)n_items * DIM * sizeof(ushort);
    const size_t meta1_off   = (tbl_off + tblu_bytes + tbli_bytes + 255) & ~(size_t)255;
    const size_t val1_off    = meta1_off + (((size_t)nnz * 4 + 255) & ~(size_t)255);
    const size_t meta2_off   = val1_off + (((size_t)nnz * 2 + 255) & ~(size_t)255);
    const size_t val2_off    = meta2_off + (((size_t)nnz * 4 + 255) & ~(size_t)255);
    const size_t need        = val2_off + (size_t)nnz * sizeof(ushort);

    if (n_users > (1 << SHIFT) || n_items > (1 << SHIFT) ||
        n_users > K1CAP * L1SZ || n_items > K1CAP * L1SZ || ws_size < need) {
        hipMemsetAsync(d_out, 0, (size_t)out_size * sizeof(float), stream);
        lightgcn_scatter_atomic<<<2048, 256, 0, stream>>>(user_emb, item_emb, rows,
                                                          cols, vals, user_out,
                                                          item_out, nnz);
        return;
    }

    int* wsi       = (int*)d_ws;
    int* counts1   = wsi + counts1_o;
    int* bases1    = wsi + bases1_o;
    int* cursor1   = wsi + cursor1_o;
    int* chunk_bad = wsi + cbad_o;
    int* rowptr    = wsi + rowptr_o;
    ushort* tblu   = (ushort*)((char*)d_ws + tbl_off);
    ushort* tbli   = tblu + (size_t)n_users * DIM;
    unsigned* meta1 = (unsigned*)((char*)d_ws + meta1_off);
    ushort*   val1  = (ushort*)((char*)d_ws + val1_off);
    unsigned* meta2 = (unsigned*)((char*)d_ws + meta2_off);
    ushort*   val2  = (ushort*)((char*)d_ws + val2_off);

    to_bf16<<<2048, 256, 0, stream>>>(user_emb, n_users * DIM, tblu);
    to_bf16<<<2048, 256, 0, stream>>>(item_emb, n_items * DIM, tbli);

    const int p1_grid = (nnz + C1 - 1) / C1;

    struct Side { const int* dest; const int* nbr; int nrows; const ushort* tbl; float* out; };
    const Side sides[2] = {
        { cols, rows, n_items, tblu, item_out },   // item side gathers USER rows
        { rows, cols, n_users, tbli, user_out },   // user side gathers ITEM rows
    };

    for (int s = 0; s < 2; ++s) {
        const Side& S = sides[s];
        const int K1 = (S.nrows + L1SZ - 1) >> L1BITS;
        const long long meanb = (long long)nnz / K1;
        int CPB = (int)((meanb + 12287) / 12288);
        if (CPB < 1) CPB = 1;
        if (CPB > CPBMAX) CPB = CPBMAX;
        hipMemsetAsync(counts1, 0, (size_t)K1 * sizeof(int), stream);
        count1_kernel<<<1024, 256, 0, stream>>>(S.dest, nnz, K1, counts1);
        exscan_block<<<1, 1024, 0, stream>>>(counts1, K1, bases1, cursor1);
        p1_kernel<<<p1_grid, P1T, 0, stream>>>(S.dest, S.nbr, vals, nnz, K1,
                                               cursor1, meta1, val1);
        rowsort_kernel<<<K1 * CPB, RSTH, 0, stream>>>(meta1, val1, bases1, counts1,
                                                      CPB, rowptr, chunk_bad,
                                                      meta2, val2);
        const int acc_grid = K1 * (L1SZ / 4);   // 4 rows (waves) per block
        switch (CPB) {
            case 1: acc_kernel<1><<<acc_grid, 256, 0, stream>>>(S.tbl, meta2, val2, rowptr, chunk_bad, S.nrows, S.out); break;
            case 2: acc_kernel<2><<<acc_grid, 256, 0, stream>>>(S.tbl, meta2, val2, rowptr, chunk_bad, S.nrows, S.out); break;
            case 3: acc_kernel<3><<<acc_grid, 256, 0, stream>>>(S.tbl, meta2, val2, rowptr, chunk_bad, S.nrows, S.out); break;
            case 4: acc_kernel<4><<<acc_grid, 256, 0, stream>>>(S.tbl, meta2, val2, rowptr, chunk_bad, S.nrows, S.out); break;
            case 5: acc_kernel<5><<<acc_grid, 256, 0, stream>>>(S.tbl, meta2, val2, rowptr, chunk_bad, S.nrows, S.out); break;
            case 6: acc_kernel<6><<<acc_grid, 256, 0, stream>>>(S.tbl, meta2, val2, rowptr, chunk_bad, S.nrows, S.out); break;
            case 7: acc_kernel<7><<<acc_grid, 256, 0, stream>>>(S.tbl, meta2, val2, rowptr, chunk_bad, S.nrows, S.out); break;
            default: acc_kernel<8><<<acc_grid, 256, 0, stream>>>(S.tbl, meta2, val2, rowptr, chunk_bad, S.nrows, S.out); break;
        }
    }
}

// Round 14
// 616.713 us; speedup vs baseline: 1.8256x; 1.3447x over previous
//
#include <hip/hip_runtime.h>

// LightGCN conv via exact 2-level counting sort + per-row register accumulate.
// Per side (sequential, shares buffers):
//   count1 -> exscan1 -> p1 (block-local LDS counting sort by 256-row bucket,
//            claim spans, DESTINATION-ORDER coalesced writeback)
//   rowsort (block-local sort by row within bucket chunk -> rowptr)
//   acc<CPB> (one wave per row; hoisted segment bounds; quarter-wave ushort4
//            gathers = 4 edges per VMEM instruction)
// R14: R13's p1 wrote 350MB vs 60 ideal (scattered frontier writes evicted
// partially-dirty from L2 by streaming reads). p1 now stages the chunk
// bucket-major in LDS and writes back in destination order (the fix that
// worked for refine/rowsort).

constexpr int DIM    = 64;
constexpr int L1BITS = 8;
constexpr int L1SZ   = 1 << L1BITS;       // rows per L1 bucket
constexpr int SHIFT  = 17;                // bits for neighbor id
constexpr unsigned NMASK = (1u << SHIFT) - 1;
constexpr int C1     = 8192;              // edges per p1 block
constexpr int P1T    = 512;               // p1 threads
constexpr int KP1    = C1 / P1T;          // 16 register edges per p1 thread
constexpr int K1CAP  = 512;               // max L1 buckets per side
constexpr int RSTH   = 1024;              // rowsort threads
constexpr int KMAX   = 14;                // register pairs per rowsort thread
constexpr int CAPC   = RSTH * KMAX;       // 14336 max pairs per chunk
constexpr int GROUPS = 2;                 // rowsort group passes
constexpr int GRS    = L1SZ / GROUPS;     // 128
constexpr int SCAP   = 8192;              // rowsort LDS stage capacity
constexpr int CPBMAX = 8;

__device__ __forceinline__ ushort f2bf(unsigned u) {
    return (ushort)((u + 0x7FFFu + ((u >> 16) & 1u)) >> 16);
}
__device__ __forceinline__ float bf2f(ushort b) {
    return __uint_as_float((unsigned)b << 16);
}

// ---------------- fallback (round-1) atomic kernel ----------------
__global__ void lightgcn_scatter_atomic(const float* __restrict__ user_emb,
                                        const float* __restrict__ item_emb,
                                        const int* __restrict__ rows,
                                        const int* __restrict__ cols,
                                        const float* __restrict__ vals,
                                        float* __restrict__ user_out,
                                        float* __restrict__ item_out,
                                        int nnz) {
    const int lane   = threadIdx.x & 63;
    const int wave   = (blockIdx.x * blockDim.x + threadIdx.x) >> 6;
    const int nwaves = (gridDim.x * blockDim.x) >> 6;
    for (int e = wave; e < nnz; e += nwaves) {
        const int r = rows[e];
        const int c = cols[e];
        const float v = vals[e];
        atomicAdd(&user_out[(size_t)r * DIM + lane], v * item_emb[(size_t)c * DIM + lane]);
        atomicAdd(&item_out[(size_t)c * DIM + lane], v * user_emb[(size_t)r * DIM + lane]);
    }
}

// ---------------- bf16 table conversion (RNE) ----------------
__global__ void to_bf16(const float* __restrict__ a, int n, ushort* __restrict__ o) {
    int i = blockIdx.x * blockDim.x + threadIdx.x;
    const int s = gridDim.x * blockDim.x;
    for (; i < n; i += s) o[i] = f2bf(__float_as_uint(a[i]));
}

// ---------------- count1: L1-bucket histogram (int4 loads) ----------------
__global__ __launch_bounds__(256)
void count1_kernel(const int* __restrict__ dest, int nnz, int K1,
                   int* __restrict__ counts1) {
    __shared__ int h[K1CAP * 4];
    const int tid = threadIdx.x;
    for (int t = tid; t < K1 * 4; t += 256) h[t] = 0;
    __syncthreads();
    const int rr = tid & 3;
    const int nq = nnz >> 2;
    const int4* d4 = (const int4*)dest;
    for (int i = blockIdx.x * 256 + tid; i < nq; i += gridDim.x * 256) {
        const int4 d = d4[i];
        atomicAdd(&h[((d.x >> L1BITS) << 2) | rr], 1);
        atomicAdd(&h[((d.y >> L1BITS) << 2) | rr], 1);
        atomicAdd(&h[((d.z >> L1BITS) << 2) | rr], 1);
        atomicAdd(&h[((d.w >> L1BITS) << 2) | rr], 1);
    }
    for (int i = (nq << 2) + blockIdx.x * 256 + tid; i < nnz; i += gridDim.x * 256)
        atomicAdd(&h[((dest[i] >> L1BITS) << 2) | rr], 1);
    __syncthreads();
    for (int b = tid; b < K1; b += 256) {
        const int c = h[b*4] + h[b*4+1] + h[b*4+2] + h[b*4+3];
        if (c) atomicAdd(&counts1[b], c);
    }
}

// ---------------- exscan over K1 buckets (1 block) ----------------
__global__ __launch_bounds__(1024)
void exscan_block(const int* __restrict__ src, int n,
                  int* __restrict__ base, int* __restrict__ cursor) {
    __shared__ int s[1024];
    const int tid = threadIdx.x;
    const int len = (n + 1023) >> 10;
    const int lo = min(tid * len, n);
    const int hi = min(lo + len, n);
    int sum = 0;
    for (int i = lo; i < hi; ++i) sum += src[i];
    s[tid] = sum;
    __syncthreads();
    for (int off = 1; off < 1024; off <<= 1) {
        const int t = (tid >= off) ? s[tid - off] : 0;
        __syncthreads();
        s[tid] += t;
        __syncthreads();
    }
    int run = tid ? s[tid - 1] : 0;
    for (int i = lo; i < hi; ++i) {
        const int c = src[i];
        base[i] = run; cursor[i] = run;
        run += c;
    }
}

// ---------------- p1: block-local counting sort + destination-order write ----
__global__ __launch_bounds__(P1T)
void p1_kernel(const int* __restrict__ dest, const int* __restrict__ nbr,
               const float* __restrict__ vals, int nnz, int K1,
               int* __restrict__ cursor1,
               unsigned* __restrict__ meta1, ushort* __restrict__ val1) {
    __shared__ unsigned smeta[C1];     // 32 KiB (bucket-major staged meta)
    __shared__ ushort   sval[C1];      // 16 KiB
    __shared__ ushort   sbuck[C1];     // 16 KiB (bucket id per staged slot)
    __shared__ int      h[K1CAP * 4];  // 8 KiB  (x4-replicated histogram)
    __shared__ int      gd[K1CAP];     // global span base per bucket
    __shared__ int      lstart[K1CAP]; // local exclusive start per bucket
    __shared__ int      lc[K1CAP];     // cursors
    __shared__ int      ssum[P1T];     // block scan
    const int tid = threadIdx.x;
    const int e0 = blockIdx.x * C1;
    const int e1 = min(e0 + C1, nnz);
    const int n = e1 - e0;
    for (int t = tid; t < K1 * 4; t += P1T) h[t] = 0;
    __syncthreads();
    const int rr = tid & 3;

    int   dv[KP1];
    int   nv[KP1];
    float fv[KP1];
    #pragma unroll
    for (int k = 0; k < KP1; ++k) {
        const int i = tid + k * P1T;
        if (i < n) {
            dv[k] = dest[e0 + i];
            nv[k] = nbr[e0 + i];
            fv[k] = vals[e0 + i];
            atomicAdd(&h[((dv[k] >> L1BITS) << 2) | rr], 1);
        }
    }
    __syncthreads();

    int cb = 0;
    if (tid < K1) cb = h[tid*4] + h[tid*4+1] + h[tid*4+2] + h[tid*4+3];
    ssum[tid] = cb;
    __syncthreads();
    for (int off = 1; off < P1T; off <<= 1) {
        const int t = (tid >= off) ? ssum[tid - off] : 0;
        __syncthreads();
        ssum[tid] += t;
        __syncthreads();
    }
    if (tid < K1) {
        const int excl = ssum[tid] - cb;
        lstart[tid] = excl;
        lc[tid]     = excl;
        gd[tid]     = cb ? atomicAdd(&cursor1[tid], cb) : 0;
    }
    __syncthreads();

    #pragma unroll
    for (int k = 0; k < KP1; ++k) {
        const int i = tid + k * P1T;
        if (i < n) {
            const int b = dv[k] >> L1BITS;
            const int s = atomicAdd(&lc[b], 1);
            smeta[s] = ((unsigned)(dv[k] & (L1SZ - 1)) << SHIFT) | (unsigned)nv[k];
            sval[s]  = f2bf(__float_as_uint(fv[k]));
            sbuck[s] = (ushort)b;
        }
    }
    __syncthreads();

    // destination-order writeback: consecutive i -> consecutive dst in-run
    for (int i = tid; i < n; i += P1T) {
        const int b = sbuck[i];
        const int dst = gd[b] + (i - lstart[b]);
        meta1[dst] = smeta[i];
        val1[dst]  = sval[i];
    }
}

// ---------------- rowsort: local chunk sort, contiguous writes ----------------
__global__ __launch_bounds__(RSTH)
void rowsort_kernel(const unsigned* __restrict__ meta1,
                    const ushort* __restrict__ val1,
                    const int* __restrict__ bases1,
                    const int* __restrict__ counts1,
                    int CPB, int* __restrict__ rowptr, int* __restrict__ chunk_bad,
                    unsigned* __restrict__ meta2, ushort* __restrict__ val2) {
    __shared__ unsigned smeta[SCAP];   // 32 KiB
    __shared__ ushort   sval[SCAP];    // 16 KiB
    __shared__ int      ssum[L1SZ];
    __shared__ int      cur[L1SZ];
    __shared__ int      gbad;
    const int cid = blockIdx.x;
    const int B = cid / CPB, j = cid - B * CPB;
    const int tid = threadIdx.x;
    const int nb  = counts1[B];
    const int bst = bases1[B];
    const int csz = (nb + CPB - 1) / CPB;
    const int s0 = min(bst + j * csz, bst + nb);
    const int s1 = min(s0 + csz, bst + nb);
    const int n = s1 - s0;
    int* rp = rowptr + (size_t)cid * (L1SZ + 1);

    if (n > CAPC) {   // far beyond sigma; correct slow fallback (acc filters)
        for (int i = tid; i < n; i += RSTH) {
            meta2[s0 + i] = meta1[s0 + i];
            val2[s0 + i]  = val1[s0 + i];
        }
        if (tid < L1SZ) rp[tid] = s0;
        if (tid == 0) { rp[L1SZ] = s1; chunk_bad[cid] = 1; }
        return;
    }

    if (tid < L1SZ) cur[tid] = 0;
    if (tid == 0) gbad = 0;
    __syncthreads();

    unsigned mv[KMAX];
    ushort   vv[KMAX];
    #pragma unroll
    for (int k = 0; k < KMAX; ++k) {
        const int i = tid + k * RSTH;
        if (i < n) {
            mv[k] = __builtin_nontemporal_load(&meta1[s0 + i]);
            vv[k] = __builtin_nontemporal_load(&val1[s0 + i]);
            atomicAdd(&cur[mv[k] >> SHIFT], 1);
        }
    }
    __syncthreads();
    if (tid < L1SZ) ssum[tid] = cur[tid];
    __syncthreads();
    for (int off = 1; off < L1SZ; off <<= 1) {
        int t = 0;
        if (tid < L1SZ && tid >= off) t = ssum[tid - off];
        __syncthreads();
        if (tid < L1SZ) ssum[tid] += t;
        __syncthreads();
    }
    if (tid < L1SZ) {
        const int excl = tid ? ssum[tid - 1] : 0;
        rp[tid] = s0 + excl;
        cur[tid] = excl;
    }
    if (tid == 0) rp[L1SZ] = s1;
    if (tid < GROUPS) {
        const int gs = tid ? ssum[tid * GRS - 1] : 0;
        if (ssum[(tid + 1) * GRS - 1] - gs > SCAP) gbad = 1;
    }
    __syncthreads();

    if (gbad) {   // stage overflow (way out on the tail); correct fallback
        #pragma unroll
        for (int k = 0; k < KMAX; ++k) {
            const int i = tid + k * RSTH;
            if (i < n) { meta2[s0 + i] = mv[k]; val2[s0 + i] = vv[k]; }
        }
        if (tid == 0) chunk_bad[cid] = 1;
        return;
    }
    if (tid == 0) chunk_bad[cid] = 0;

    for (int g = 0; g < GROUPS; ++g) {
        const int gs = g ? ssum[g * GRS - 1] : 0;
        const int ge = ssum[(g + 1) * GRS - 1];
        #pragma unroll
        for (int k = 0; k < KMAX; ++k) {
            const int i = tid + k * RSTH;
            if (i < n) {
                const int row = (int)(mv[k] >> SHIFT);
                if ((row >> 7) == g) {               // GRS = 128
                    const int slot = atomicAdd(&cur[row], 1);
                    smeta[slot - gs] = mv[k];
                    sval[slot - gs]  = vv[k];
                }
            }
        }
        __syncthreads();
        for (int i = tid; i < ge - gs; i += RSTH) {
            meta2[s0 + gs + i] = smeta[i];
            val2[s0 + gs + i]  = sval[i];
        }
        __syncthreads();
    }
}

// ---------------- acc: wave/row, hoisted bounds, quarter-wave ushort4 --------
template<int CPBT>
__global__ __launch_bounds__(256)
void acc_kernel(const ushort* __restrict__ tbl,
                const unsigned* __restrict__ meta2,
                const ushort* __restrict__ val2,
                const int* __restrict__ rowptr,
                const int* __restrict__ chunk_bad,
                int nrows, float* __restrict__ out) {
    const int lane = threadIdx.x & 63;
    const int q  = lane >> 4;     // quarter handles edge e+q
    const int li = lane & 15;     // dims 4*li .. 4*li+3
    const int r = (int)((blockIdx.x * blockDim.x + threadIdx.x) >> 6);
    const int B = r >> L1BITS;
    const int rlow = r & (L1SZ - 1);
    int stj[CPBT], enj[CPBT], cbj[CPBT];
    #pragma unroll
    for (int j = 0; j < CPBT; ++j) {
        const int cid = B * CPBT + j;
        const int* rp = rowptr + (size_t)cid * (L1SZ + 1);
        cbj[j] = chunk_bad[cid];
        stj[j] = rp[rlow];
        enj[j] = rp[rlow + 1];
    }
    float a0 = 0.f, a1 = 0.f, a2 = 0.f, a3 = 0.f;
    #define STEP(EI) { const unsigned m_ = meta2[EI];                          \
        const float v_ = bf2f(val2[EI]);                                       \
        const ushort4 g_ = *(const ushort4*)(tbl + (size_t)(m_ & NMASK) * DIM + 4*li); \
        a0 = fmaf(v_, bf2f(g_.x), a0); a1 = fmaf(v_, bf2f(g_.y), a1);          \
        a2 = fmaf(v_, bf2f(g_.z), a2); a3 = fmaf(v_, bf2f(g_.w), a3); }
    #pragma unroll
    for (int j = 0; j < CPBT; ++j) {
        if (__builtin_expect(cbj[j] != 0, 0)) {
            const int cid = B * CPBT + j;
            const int* rp = rowptr + (size_t)cid * (L1SZ + 1);
            const int cs = rp[0], ce = rp[L1SZ];
            for (int e = cs; e < ce; e += 4) {
                if (e + q < ce) {
                    const unsigned m_ = meta2[e + q];
                    if ((int)(m_ >> SHIFT) == rlow) {
                        const float v_ = bf2f(val2[e + q]);
                        const ushort4 g_ = *(const ushort4*)(tbl + (size_t)(m_ & NMASK) * DIM + 4*li);
                        a0 = fmaf(v_, bf2f(g_.x), a0); a1 = fmaf(v_, bf2f(g_.y), a1);
                        a2 = fmaf(v_, bf2f(g_.z), a2); a3 = fmaf(v_, bf2f(g_.w), a3);
                    }
                }
            }
        } else {
            const int en = enj[j];
            int e = stj[j];
            for (; e + 8 <= en; e += 8) { STEP(e + q); STEP(e + 4 + q); }
            if (e + 4 <= en) { STEP(e + q); e += 4; }
            if (e + q < en) STEP(e + q);
        }
    }
    #undef STEP
    a0 += __shfl_xor(a0, 16); a0 += __shfl_xor(a0, 32);
    a1 += __shfl_xor(a1, 16); a1 += __shfl_xor(a1, 32);
    a2 += __shfl_xor(a2, 16); a2 += __shfl_xor(a2, 32);
    a3 += __shfl_xor(a3, 16); a3 += __shfl_xor(a3, 32);
    if (lane < 16 && r < nrows)
        *(float4*)(out + (size_t)r * DIM + 4*li) = make_float4(a0, a1, a2, a3);
}

extern "C" void kernel_launch(void* const* d_in, const int* in_sizes, int n_in,
                              void* d_out, int out_size, void* d_ws, size_t ws_size,
                              hipStream_t stream) {
    const float* user_emb = (const float*)d_in[0];
    const float* item_emb = (const float*)d_in[1];
    const int*   rows     = (const int*)d_in[2];
    const int*   cols     = (const int*)d_in[3];
    const float* vals     = (const float*)d_in[4];

    const int nnz     = in_sizes[2];
    const int n_users = in_sizes[0] / DIM;
    const int n_items = in_sizes[1] / DIM;

    float* user_out = (float*)d_out;
    float* item_out = (float*)d_out + (size_t)in_sizes[0];

    // ---- workspace layout ----
    size_t oi = 0;
    const size_t counts1_o  = oi; oi += K1CAP;
    const size_t bases1_o   = oi; oi += K1CAP;
    const size_t cursor1_o  = oi; oi += K1CAP;
    const size_t cbad_o     = oi; oi += (size_t)K1CAP * CPBMAX;
    const size_t rowptr_o   = oi; oi += (size_t)K1CAP * CPBMAX * (L1SZ + 1);
    const size_t meta_bytes = oi * sizeof(int);
    const size_t tbl_off     = (meta_bytes + 255) & ~(size_t)255;
    const size_t tblu_bytes  = (size_t)n_users * DIM * sizeof(ushort);
    const size_t tbli_bytes  = (size_t)n_items * DIM * sizeof(ushort);
    const size_t meta1_off   = (tbl_off + tblu_bytes + tbli_bytes + 255) & ~(size_t)255;
    const size_t val1_off    = meta1_off + (((size_t)nnz * 4 + 255) & ~(size_t)255);
    const size_t meta2_off   = val1_off + (((size_t)nnz * 2 + 255) & ~(size_t)255);
    const size_t val2_off    = meta2_off + (((size_t)nnz * 4 + 255) & ~(size_t)255);
    const size_t need        = val2_off + (size_t)nnz * sizeof(ushort);

    if (n_users > (1 << SHIFT) || n_items > (1 << SHIFT) ||
        n_users > K1CAP * L1SZ || n_items > K1CAP * L1SZ || ws_size < need) {
        hipMemsetAsync(d_out, 0, (size_t)out_size * sizeof(float), stream);
        lightgcn_scatter_atomic<<<2048, 256, 0, stream>>>(user_emb, item_emb, rows,
                                                          cols, vals, user_out,
                                                          item_out, nnz);
        return;
    }

    int* wsi       = (int*)d_ws;
    int* counts1   = wsi + counts1_o;
    int* bases1    = wsi + bases1_o;
    int* cursor1   = wsi + cursor1_o;
    int* chunk_bad = wsi + cbad_o;
    int* rowptr    = wsi + rowptr_o;
    ushort* tblu   = (ushort*)((char*)d_ws + tbl_off);
    ushort* tbli   = tblu + (size_t)n_users * DIM;
    unsigned* meta1 = (unsigned*)((char*)d_ws + meta1_off);
    ushort*   val1  = (ushort*)((char*)d_ws + val1_off);
    unsigned* meta2 = (unsigned*)((char*)d_ws + meta2_off);
    ushort*   val2  = (ushort*)((char*)d_ws + val2_off);

    to_bf16<<<2048, 256, 0, stream>>>(user_emb, n_users * DIM, tblu);
    to_bf16<<<2048, 256, 0, stream>>>(item_emb, n_items * DIM, tbli);

    const int p1_grid = (nnz + C1 - 1) / C1;

    struct Side { const int* dest; const int* nbr; int nrows; const ushort* tbl; float* out; };
    const Side sides[2] = {
        { cols, rows, n_items, tblu, item_out },   // item side gathers USER rows
        { rows, cols, n_users, tbli, user_out },   // user side gathers ITEM rows
    };

    for (int s = 0; s < 2; ++s) {
        const Side& S = sides[s];
        const int K1 = (S.nrows + L1SZ - 1) >> L1BITS;
        const long long meanb = (long long)nnz / K1;
        int CPB = (int)((meanb + 12287) / 12288);
        if (CPB < 1) CPB = 1;
        if (CPB > CPBMAX) CPB = CPBMAX;
        hipMemsetAsync(counts1, 0, (size_t)K1 * sizeof(int), stream);
        count1_kernel<<<1024, 256, 0, stream>>>(S.dest, nnz, K1, counts1);
        exscan_block<<<1, 1024, 0, stream>>>(counts1, K1, bases1, cursor1);
        p1_kernel<<<p1_grid, P1T, 0, stream>>>(S.dest, S.nbr, vals, nnz, K1,
                                               cursor1, meta1, val1);
        rowsort_kernel<<<K1 * CPB, RSTH, 0, stream>>>(meta1, val1, bases1, counts1,
                                                      CPB, rowptr, chunk_bad,
                                                      meta2, val2);
        const int acc_grid = K1 * (L1SZ / 4);   // 4 rows (waves) per block
        switch (CPB) {
            case 1: acc_kernel<1><<<acc_grid, 256, 0, stream>>>(S.tbl, meta2, val2, rowptr, chunk_bad, S.nrows, S.out); break;
            case 2: acc_kernel<2><<<acc_grid, 256, 0, stream>>>(S.tbl, meta2, val2, rowptr, chunk_bad, S.nrows, S.out); break;
            case 3: acc_kernel<3><<<acc_grid, 256, 0, stream>>>(S.tbl, meta2, val2, rowptr, chunk_bad, S.nrows, S.out); break;
            case 4: acc_kernel<4><<<acc_grid, 256, 0, stream>>>(S.tbl, meta2, val2, rowptr, chunk_bad, S.nrows, S.out); break;
            case 5: acc_kernel<5><<<acc_grid, 256, 0, stream>>>(S.tbl, meta2, val2, rowptr, chunk_bad, S.nrows, S.out); break;
            case 6: acc_kernel<6><<<acc_grid, 256, 0, stream>>>(S.tbl, meta2, val2, rowptr, chunk_bad, S.nrows, S.out); break;
            case 7: acc_kernel<7><<<acc_grid, 256, 0, stream>>>(S.tbl, meta2, val2, rowptr, chunk_bad, S.nrows, S.out); break;
            default: acc_kernel<8><<<acc_grid, 256, 0, stream>>>(S.tbl, meta2, val2, rowptr, chunk_bad, S.nrows, S.out); break;
        }
    }
}

// Round 15
// 537.234 us; speedup vs baseline: 2.0957x; 1.1479x over previous
//
#include <hip/hip_runtime.h>

// LightGCN conv via exact 2-level counting sort + per-row register accumulate.
// Per side (sequential, shares buffers):
//   count1 -> exscan1 -> p1 (block-local LDS counting sort by 256-row bucket,
//            claim spans, destination-order coalesced writeback)
//   rowsort (block-local sort by row within bucket chunk -> rowptr)
//   acc<CPB> (one wave per row; hoisted segment bounds; EIGHTH-wave ushort8
//            gathers = 8 edges per VMEM instruction)
// R15: R14's acc (175us/side) showed VALUBusy 44% / 2.9TB/s / Occ 78% --
// neither pipe saturated -> instruction+latency mixed. 8 lanes/edge halves
// VMEM instrs, addressing VALU, and loop overhead at identical traffic.

constexpr int DIM    = 64;
constexpr int L1BITS = 8;
constexpr int L1SZ   = 1 << L1BITS;       // rows per L1 bucket
constexpr int SHIFT  = 17;                // bits for neighbor id
constexpr unsigned NMASK = (1u << SHIFT) - 1;
constexpr int C1     = 8192;              // edges per p1 block
constexpr int P1T    = 512;               // p1 threads
constexpr int KP1    = C1 / P1T;          // 16 register edges per p1 thread
constexpr int K1CAP  = 512;               // max L1 buckets per side
constexpr int RSTH   = 1024;              // rowsort threads
constexpr int KMAX   = 14;                // register pairs per rowsort thread
constexpr int CAPC   = RSTH * KMAX;       // 14336 max pairs per chunk
constexpr int GROUPS = 2;                 // rowsort group passes
constexpr int GRS    = L1SZ / GROUPS;     // 128
constexpr int SCAP   = 8192;              // rowsort LDS stage capacity
constexpr int CPBMAX = 8;

typedef unsigned short us8 __attribute__((ext_vector_type(8)));

__device__ __forceinline__ ushort f2bf(unsigned u) {
    return (ushort)((u + 0x7FFFu + ((u >> 16) & 1u)) >> 16);
}
__device__ __forceinline__ float bf2f(ushort b) {
    return __uint_as_float((unsigned)b << 16);
}

// ---------------- fallback (round-1) atomic kernel ----------------
__global__ void lightgcn_scatter_atomic(const float* __restrict__ user_emb,
                                        const float* __restrict__ item_emb,
                                        const int* __restrict__ rows,
                                        const int* __restrict__ cols,
                                        const float* __restrict__ vals,
                                        float* __restrict__ user_out,
                                        float* __restrict__ item_out,
                                        int nnz) {
    const int lane   = threadIdx.x & 63;
    const int wave   = (blockIdx.x * blockDim.x + threadIdx.x) >> 6;
    const int nwaves = (gridDim.x * blockDim.x) >> 6;
    for (int e = wave; e < nnz; e += nwaves) {
        const int r = rows[e];
        const int c = cols[e];
        const float v = vals[e];
        atomicAdd(&user_out[(size_t)r * DIM + lane], v * item_emb[(size_t)c * DIM + lane]);
        atomicAdd(&item_out[(size_t)c * DIM + lane], v * user_emb[(size_t)r * DIM + lane]);
    }
}

// ---------------- bf16 table conversion (RNE) ----------------
__global__ void to_bf16(const float* __restrict__ a, int n, ushort* __restrict__ o) {
    int i = blockIdx.x * blockDim.x + threadIdx.x;
    const int s = gridDim.x * blockDim.x;
    for (; i < n; i += s) o[i] = f2bf(__float_as_uint(a[i]));
}

// ---------------- count1: L1-bucket histogram (int4 loads) ----------------
__global__ __launch_bounds__(256)
void count1_kernel(const int* __restrict__ dest, int nnz, int K1,
                   int* __restrict__ counts1) {
    __shared__ int h[K1CAP * 4];
    const int tid = threadIdx.x;
    for (int t = tid; t < K1 * 4; t += 256) h[t] = 0;
    __syncthreads();
    const int rr = tid & 3;
    const int nq = nnz >> 2;
    const int4* d4 = (const int4*)dest;
    for (int i = blockIdx.x * 256 + tid; i < nq; i += gridDim.x * 256) {
        const int4 d = d4[i];
        atomicAdd(&h[((d.x >> L1BITS) << 2) | rr], 1);
        atomicAdd(&h[((d.y >> L1BITS) << 2) | rr], 1);
        atomicAdd(&h[((d.z >> L1BITS) << 2) | rr], 1);
        atomicAdd(&h[((d.w >> L1BITS) << 2) | rr], 1);
    }
    for (int i = (nq << 2) + blockIdx.x * 256 + tid; i < nnz; i += gridDim.x * 256)
        atomicAdd(&h[((dest[i] >> L1BITS) << 2) | rr], 1);
    __syncthreads();
    for (int b = tid; b < K1; b += 256) {
        const int c = h[b*4] + h[b*4+1] + h[b*4+2] + h[b*4+3];
        if (c) atomicAdd(&counts1[b], c);
    }
}

// ---------------- exscan over K1 buckets (1 block) ----------------
__global__ __launch_bounds__(1024)
void exscan_block(const int* __restrict__ src, int n,
                  int* __restrict__ base, int* __restrict__ cursor) {
    __shared__ int s[1024];
    const int tid = threadIdx.x;
    const int len = (n + 1023) >> 10;
    const int lo = min(tid * len, n);
    const int hi = min(lo + len, n);
    int sum = 0;
    for (int i = lo; i < hi; ++i) sum += src[i];
    s[tid] = sum;
    __syncthreads();
    for (int off = 1; off < 1024; off <<= 1) {
        const int t = (tid >= off) ? s[tid - off] : 0;
        __syncthreads();
        s[tid] += t;
        __syncthreads();
    }
    int run = tid ? s[tid - 1] : 0;
    for (int i = lo; i < hi; ++i) {
        const int c = src[i];
        base[i] = run; cursor[i] = run;
        run += c;
    }
}

// ---------------- p1: block-local counting sort + destination-order write ----
__global__ __launch_bounds__(P1T)
void p1_kernel(const int* __restrict__ dest, const int* __restrict__ nbr,
               const float* __restrict__ vals, int nnz, int K1,
               int* __restrict__ cursor1,
               unsigned* __restrict__ meta1, ushort* __restrict__ val1) {
    __shared__ unsigned smeta[C1];     // 32 KiB (bucket-major staged meta)
    __shared__ ushort   sval[C1];      // 16 KiB
    __shared__ ushort   sbuck[C1];     // 16 KiB (bucket id per staged slot)
    __shared__ int      h[K1CAP * 4];  // 8 KiB  (x4-replicated histogram)
    __shared__ int      gd[K1CAP];     // global span base per bucket
    __shared__ int      lstart[K1CAP]; // local exclusive start per bucket
    __shared__ int      lc[K1CAP];     // cursors
    __shared__ int      ssum[P1T];     // block scan
    const int tid = threadIdx.x;
    const int e0 = blockIdx.x * C1;
    const int e1 = min(e0 + C1, nnz);
    const int n = e1 - e0;
    for (int t = tid; t < K1 * 4; t += P1T) h[t] = 0;
    __syncthreads();
    const int rr = tid & 3;

    int   dv[KP1];
    int   nv[KP1];
    float fv[KP1];
    #pragma unroll
    for (int k = 0; k < KP1; ++k) {
        const int i = tid + k * P1T;
        if (i < n) {
            dv[k] = dest[e0 + i];
            nv[k] = nbr[e0 + i];
            fv[k] = vals[e0 + i];
            atomicAdd(&h[((dv[k] >> L1BITS) << 2) | rr], 1);
        }
    }
    __syncthreads();

    int cb = 0;
    if (tid < K1) cb = h[tid*4] + h[tid*4+1] + h[tid*4+2] + h[tid*4+3];
    ssum[tid] = cb;
    __syncthreads();
    for (int off = 1; off < P1T; off <<= 1) {
        const int t = (tid >= off) ? ssum[tid - off] : 0;
        __syncthreads();
        ssum[tid] += t;
        __syncthreads();
    }
    if (tid < K1) {
        const int excl = ssum[tid] - cb;
        lstart[tid] = excl;
        lc[tid]     = excl;
        gd[tid]     = cb ? atomicAdd(&cursor1[tid], cb) : 0;
    }
    __syncthreads();

    #pragma unroll
    for (int k = 0; k < KP1; ++k) {
        const int i = tid + k * P1T;
        if (i < n) {
            const int b = dv[k] >> L1BITS;
            const int s = atomicAdd(&lc[b], 1);
            smeta[s] = ((unsigned)(dv[k] & (L1SZ - 1)) << SHIFT) | (unsigned)nv[k];
            sval[s]  = f2bf(__float_as_uint(fv[k]));
            sbuck[s] = (ushort)b;
        }
    }
    __syncthreads();

    // destination-order writeback: consecutive i -> consecutive dst in-run
    for (int i = tid; i < n; i += P1T) {
        const int b = sbuck[i];
        const int dst = gd[b] + (i - lstart[b]);
        meta1[dst] = smeta[i];
        val1[dst]  = sval[i];
    }
}

// ---------------- rowsort: local chunk sort, contiguous writes ----------------
__global__ __launch_bounds__(RSTH)
void rowsort_kernel(const unsigned* __restrict__ meta1,
                    const ushort* __restrict__ val1,
                    const int* __restrict__ bases1,
                    const int* __restrict__ counts1,
                    int CPB, int* __restrict__ rowptr, int* __restrict__ chunk_bad,
                    unsigned* __restrict__ meta2, ushort* __restrict__ val2) {
    __shared__ unsigned smeta[SCAP];   // 32 KiB
    __shared__ ushort   sval[SCAP];    // 16 KiB
    __shared__ int      ssum[L1SZ];
    __shared__ int      cur[L1SZ];
    __shared__ int      gbad;
    const int cid = blockIdx.x;
    const int B = cid / CPB, j = cid - B * CPB;
    const int tid = threadIdx.x;
    const int nb  = counts1[B];
    const int bst = bases1[B];
    const int csz = (nb + CPB - 1) / CPB;
    const int s0 = min(bst + j * csz, bst + nb);
    const int s1 = min(s0 + csz, bst + nb);
    const int n = s1 - s0;
    int* rp = rowptr + (size_t)cid * (L1SZ + 1);

    if (n > CAPC) {   // far beyond sigma; correct slow fallback (acc filters)
        for (int i = tid; i < n; i += RSTH) {
            meta2[s0 + i] = meta1[s0 + i];
            val2[s0 + i]  = val1[s0 + i];
        }
        if (tid < L1SZ) rp[tid] = s0;
        if (tid == 0) { rp[L1SZ] = s1; chunk_bad[cid] = 1; }
        return;
    }

    if (tid < L1SZ) cur[tid] = 0;
    if (tid == 0) gbad = 0;
    __syncthreads();

    unsigned mv[KMAX];
    ushort   vv[KMAX];
    #pragma unroll
    for (int k = 0; k < KMAX; ++k) {
        const int i = tid + k * RSTH;
        if (i < n) {
            mv[k] = __builtin_nontemporal_load(&meta1[s0 + i]);
            vv[k] = __builtin_nontemporal_load(&val1[s0 + i]);
            atomicAdd(&cur[mv[k] >> SHIFT], 1);
        }
    }
    __syncthreads();
    if (tid < L1SZ) ssum[tid] = cur[tid];
    __syncthreads();
    for (int off = 1; off < L1SZ; off <<= 1) {
        int t = 0;
        if (tid < L1SZ && tid >= off) t = ssum[tid - off];
        __syncthreads();
        if (tid < L1SZ) ssum[tid] += t;
        __syncthreads();
    }
    if (tid < L1SZ) {
        const int excl = tid ? ssum[tid - 1] : 0;
        rp[tid] = s0 + excl;
        cur[tid] = excl;
    }
    if (tid == 0) rp[L1SZ] = s1;
    if (tid < GROUPS) {
        const int gs = tid ? ssum[tid * GRS - 1] : 0;
        if (ssum[(tid + 1) * GRS - 1] - gs > SCAP) gbad = 1;
    }
    __syncthreads();

    if (gbad) {   // stage overflow (way out on the tail); correct fallback
        #pragma unroll
        for (int k = 0; k < KMAX; ++k) {
            const int i = tid + k * RSTH;
            if (i < n) { meta2[s0 + i] = mv[k]; val2[s0 + i] = vv[k]; }
        }
        if (tid == 0) chunk_bad[cid] = 1;
        return;
    }
    if (tid == 0) chunk_bad[cid] = 0;

    for (int g = 0; g < GROUPS; ++g) {
        const int gs = g ? ssum[g * GRS - 1] : 0;
        const int ge = ssum[(g + 1) * GRS - 1];
        #pragma unroll
        for (int k = 0; k < KMAX; ++k) {
            const int i = tid + k * RSTH;
            if (i < n) {
                const int row = (int)(mv[k] >> SHIFT);
                if ((row >> 7) == g) {               // GRS = 128
                    const int slot = atomicAdd(&cur[row], 1);
                    smeta[slot - gs] = mv[k];
                    sval[slot - gs]  = vv[k];
                }
            }
        }
        __syncthreads();
        for (int i = tid; i < ge - gs; i += RSTH) {
            meta2[s0 + gs + i] = smeta[i];
            val2[s0 + gs + i]  = sval[i];
        }
        __syncthreads();
    }
}

// ---------------- acc: wave/row, hoisted bounds, eighth-wave ushort8 ---------
template<int CPBT>
__global__ __launch_bounds__(256)
void acc_kernel(const ushort* __restrict__ tbl,
                const unsigned* __restrict__ meta2,
                const ushort* __restrict__ val2,
                const int* __restrict__ rowptr,
                const int* __restrict__ chunk_bad,
                int nrows, float* __restrict__ out) {
    const int lane = threadIdx.x & 63;
    const int oc  = lane >> 3;    // eighth handles edge e+oc
    const int li  = lane & 7;     // dims 8*li .. 8*li+7
    const int r = (int)((blockIdx.x * blockDim.x + threadIdx.x) >> 6);
    const int B = r >> L1BITS;
    const int rlow = r & (L1SZ - 1);
    int stj[CPBT], enj[CPBT], cbj[CPBT];
    #pragma unroll
    for (int j = 0; j < CPBT; ++j) {
        const int cid = B * CPBT + j;
        const int* rp = rowptr + (size_t)cid * (L1SZ + 1);
        cbj[j] = chunk_bad[cid];
        stj[j] = rp[rlow];
        enj[j] = rp[rlow + 1];
    }
    float a0 = 0.f, a1 = 0.f, a2 = 0.f, a3 = 0.f;
    float a4 = 0.f, a5 = 0.f, a6 = 0.f, a7 = 0.f;
    #define STEP(EI) { const unsigned m_ = meta2[EI];                          \
        const float v_ = bf2f(val2[EI]);                                       \
        const us8 g_ = *(const us8*)(tbl + (size_t)(m_ & NMASK) * DIM + 8*li); \
        a0 = fmaf(v_, bf2f(g_[0]), a0); a1 = fmaf(v_, bf2f(g_[1]), a1);        \
        a2 = fmaf(v_, bf2f(g_[2]), a2); a3 = fmaf(v_, bf2f(g_[3]), a3);        \
        a4 = fmaf(v_, bf2f(g_[4]), a4); a5 = fmaf(v_, bf2f(g_[5]), a5);        \
        a6 = fmaf(v_, bf2f(g_[6]), a6); a7 = fmaf(v_, bf2f(g_[7]), a7); }
    #pragma unroll
    for (int j = 0; j < CPBT; ++j) {
        if (__builtin_expect(cbj[j] != 0, 0)) {
            const int cid = B * CPBT + j;
            const int* rp = rowptr + (size_t)cid * (L1SZ + 1);
            const int cs = rp[0], ce = rp[L1SZ];
            for (int e = cs; e < ce; e += 8) {
                if (e + oc < ce) {
                    const unsigned m_ = meta2[e + oc];
                    if ((int)(m_ >> SHIFT) == rlow) {
                        const float v_ = bf2f(val2[e + oc]);
                        const us8 g_ = *(const us8*)(tbl + (size_t)(m_ & NMASK) * DIM + 8*li);
                        a0 = fmaf(v_, bf2f(g_[0]), a0); a1 = fmaf(v_, bf2f(g_[1]), a1);
                        a2 = fmaf(v_, bf2f(g_[2]), a2); a3 = fmaf(v_, bf2f(g_[3]), a3);
                        a4 = fmaf(v_, bf2f(g_[4]), a4); a5 = fmaf(v_, bf2f(g_[5]), a5);
                        a6 = fmaf(v_, bf2f(g_[6]), a6); a7 = fmaf(v_, bf2f(g_[7]), a7);
                    }
                }
            }
        } else {
            const int en = enj[j];
            int e = stj[j];
            for (; e + 16 <= en; e += 16) { STEP(e + oc); STEP(e + 8 + oc); }
            if (e + 8 <= en) { STEP(e + oc); e += 8; }
            if (e + oc < en) STEP(e + oc);
        }
    }
    #undef STEP
    a0 += __shfl_xor(a0, 8); a0 += __shfl_xor(a0, 16); a0 += __shfl_xor(a0, 32);
    a1 += __shfl_xor(a1, 8); a1 += __shfl_xor(a1, 16); a1 += __shfl_xor(a1, 32);
    a2 += __shfl_xor(a2, 8); a2 += __shfl_xor(a2, 16); a2 += __shfl_xor(a2, 32);
    a3 += __shfl_xor(a3, 8); a3 += __shfl_xor(a3, 16); a3 += __shfl_xor(a3, 32);
    a4 += __shfl_xor(a4, 8); a4 += __shfl_xor(a4, 16); a4 += __shfl_xor(a4, 32);
    a5 += __shfl_xor(a5, 8); a5 += __shfl_xor(a5, 16); a5 += __shfl_xor(a5, 32);
    a6 += __shfl_xor(a6, 8); a6 += __shfl_xor(a6, 16); a6 += __shfl_xor(a6, 32);
    a7 += __shfl_xor(a7, 8); a7 += __shfl_xor(a7, 16); a7 += __shfl_xor(a7, 32);
    if (lane < 8 && r < nrows) {
        float* op = out + (size_t)r * DIM + 8*li;
        *(float4*)(op)     = make_float4(a0, a1, a2, a3);
        *(float4*)(op + 4) = make_float4(a4, a5, a6, a7);
    }
}

extern "C" void kernel_launch(void* const* d_in, const int* in_sizes, int n_in,
                              void* d_out, int out_size, void* d_ws, size_t ws_size,
                              hipStream_t stream) {
    const float* user_emb = (const float*)d_in[0];
    const float* item_emb = (const float*)d_in[1];
    const int*   rows     = (const int*)d_in[2];
    const int*   cols     = (const int*)d_in[3];
    const float* vals     = (const float*)d_in[4];

    const int nnz     = in_sizes[2];
    const int n_users = in_sizes[0] / DIM;
    const int n_items = in_sizes[1] / DIM;

    float* user_out = (float*)d_out;
    float* item_out = (float*)d_out + (size_t)in_sizes[0];

    // ---- workspace layout ----
    size_t oi = 0;
    const size_t counts1_o  = oi; oi += K1CAP;
    const size_t bases1_o   = oi; oi += K1CAP;
    const size_t cursor1_o  = oi; oi += K1CAP;
    const size_t cbad_o     = oi; oi += (size_t)K1CAP * CPBMAX;
    const size_t rowptr_o   = oi; oi += (size_t)K1CAP * CPBMAX * (L1SZ + 1);
    const size_t meta_bytes = oi * sizeof(int);
    const size_t tbl_off     = (meta_bytes + 255) & ~(size_t)255;
    const size_t tblu_bytes  = (size_t)n_users * DIM * sizeof(ushort);
    const size_t tbli_bytes  = (size_t)n_items * DIM * sizeof(ushort);
    const size_t meta1_off   = (tbl_off + tblu_bytes + tbli_bytes + 255) & ~(size_t)255;
    const size_t val1_off    = meta1_off + (((size_t)nnz * 4 + 255) & ~(size_t)255);
    const size_t meta2_off   = val1_off + (((size_t)nnz * 2 + 255) & ~(size_t)255);
    const size_t val2_off    = meta2_off + (((size_t)nnz * 4 + 255) & ~(size_t)255);
    const size_t need        = val2_off + (size_t)nnz * sizeof(ushort);

    if (n_users > (1 << SHIFT) || n_items > (1 << SHIFT) ||
        n_users > K1CAP * L1SZ || n_items > K1CAP * L1SZ || ws_size < need) {
        hipMemsetAsync(d_out, 0, (size_t)out_size * sizeof(float), stream);
        lightgcn_scatter_atomic<<<2048, 256, 0, stream>>>(user_emb, item_emb, rows,
                                                          cols, vals, user_out,
                                                          item_out, nnz);
        return;
    }

    int* wsi       = (int*)d_ws;
    int* counts1   = wsi + counts1_o;
    int* bases1    = wsi + bases1_o;
    int* cursor1   = wsi + cursor1_o;
    int* chunk_bad = wsi + cbad_o;
    int* rowptr    = wsi + rowptr_o;
    ushort* tblu   = (ushort*)((char*)d_ws + tbl_off);
    ushort* tbli   = tblu + (size_t)n_users * DIM;
    unsigned* meta1 = (unsigned*)((char*)d_ws + meta1_off);
    ushort*   val1  = (ushort*)((char*)d_ws + val1_off);
    unsigned* meta2 = (unsigned*)((char*)d_ws + meta2_off);
    ushort*   val2  = (ushort*)((char*)d_ws + val2_off);

    to_bf16<<<2048, 256, 0, stream>>>(user_emb, n_users * DIM, tblu);
    to_bf16<<<2048, 256, 0, stream>>>(item_emb, n_items * DIM, tbli);

    const int p1_grid = (nnz + C1 - 1) / C1;

    struct Side { const int* dest; const int* nbr; int nrows; const ushort* tbl; float* out; };
    const Side sides[2] = {
        { cols, rows, n_items, tblu, item_out },   // item side gathers USER rows
        { rows, cols, n_users, tbli, user_out },   // user side gathers ITEM rows
    };

    for (int s = 0; s < 2; ++s) {
        const Side& S = sides[s];
        const int K1 = (S.nrows + L1SZ - 1) >> L1BITS;
        const long long meanb = (long long)nnz / K1;
        int CPB = (int)((meanb + 12287) / 12288);
        if (CPB < 1) CPB = 1;
        if (CPB > CPBMAX) CPB = CPBMAX;
        hipMemsetAsync(counts1, 0, (size_t)K1 * sizeof(int), stream);
        count1_kernel<<<1024, 256, 0, stream>>>(S.dest, nnz, K1, counts1);
        exscan_block<<<1, 1024, 0, stream>>>(counts1, K1, bases1, cursor1);
        p1_kernel<<<p1_grid, P1T, 0, stream>>>(S.dest, S.nbr, vals, nnz, K1,
                                               cursor1, meta1, val1);
        rowsort_kernel<<<K1 * CPB, RSTH, 0, stream>>>(meta1, val1, bases1, counts1,
                                                      CPB, rowptr, chunk_bad,
                                                      meta2, val2);
        const int acc_grid = K1 * (L1SZ / 4);   // 4 rows (waves) per block
        switch (CPB) {
            case 1: acc_kernel<1><<<acc_grid, 256, 0, stream>>>(S.tbl, meta2, val2, rowptr, chunk_bad, S.nrows, S.out); break;
            case 2: acc_kernel<2><<<acc_grid, 256, 0, stream>>>(S.tbl, meta2, val2, rowptr, chunk_bad, S.nrows, S.out); break;
            case 3: acc_kernel<3><<<acc_grid, 256, 0, stream>>>(S.tbl, meta2, val2, rowptr, chunk_bad, S.nrows, S.out); break;
            case 4: acc_kernel<4><<<acc_grid, 256, 0, stream>>>(S.tbl, meta2, val2, rowptr, chunk_bad, S.nrows, S.out); break;
            case 5: acc_kernel<5><<<acc_grid, 256, 0, stream>>>(S.tbl, meta2, val2, rowptr, chunk_bad, S.nrows, S.out); break;
            case 6: acc_kernel<6><<<acc_grid, 256, 0, stream>>>(S.tbl, meta2, val2, rowptr, chunk_bad, S.nrows, S.out); break;
            case 7: acc_kernel<7><<<acc_grid, 256, 0, stream>>>(S.tbl, meta2, val2, rowptr, chunk_bad, S.nrows, S.out); break;
            default: acc_kernel<8><<<acc_grid, 256, 0, stream>>>(S.tbl, meta2, val2, rowptr, chunk_bad, S.nrows, S.out); break;
        }
    }
}

// Round 16
// 482.178 us; speedup vs baseline: 2.3350x; 1.1142x over previous
//
#include <hip/hip_runtime.h>

// LightGCN conv via exact 2-level counting sort + per-row register accumulate.
// Per side (sequential, shares buffers):
//   init_cursor (cursor1[b] = b*span; FIXED padded spans replace count1+exscan)
//   p1      (block-local LDS counting sort by 256-row bucket, claim spans,
//            destination-order coalesced writeback)
//   rowsort (block-local sort by row within bucket chunk -> rowptr; bucket
//            count derived as cursor1[B] - B*span)
//   acc<CPB> (one wave per row; hoisted segment bounds; eighth-wave ushort8
//            gathers = 8 edges per VMEM instruction)
// R16: count1 (40MB re-read/side) + exscan existed only to produce bucket
// bases. span = mean + 16sigma + 256 makes bases = b*span analytically;
// p1's final cursor gives exact counts. ~80us of pipeline deleted.

constexpr int DIM    = 64;
constexpr int L1BITS = 8;
constexpr int L1SZ   = 1 << L1BITS;       // rows per L1 bucket
constexpr int SHIFT  = 17;                // bits for neighbor id
constexpr unsigned NMASK = (1u << SHIFT) - 1;
constexpr int C1     = 8192;              // edges per p1 block
constexpr int P1T    = 512;               // p1 threads
constexpr int KP1    = C1 / P1T;          // 16 register edges per p1 thread
constexpr int K1CAP  = 512;               // max L1 buckets per side
constexpr int RSTH   = 1024;              // rowsort threads
constexpr int KMAX   = 14;                // register pairs per rowsort thread
constexpr int CAPC   = RSTH * KMAX;       // 14336 max pairs per chunk
constexpr int GROUPS = 2;                 // rowsort group passes
constexpr int GRS    = L1SZ / GROUPS;     // 128
constexpr int SCAP   = 8192;              // rowsort LDS stage capacity
constexpr int CPBMAX = 8;

typedef unsigned short us8 __attribute__((ext_vector_type(8)));

__device__ __forceinline__ ushort f2bf(unsigned u) {
    return (ushort)((u + 0x7FFFu + ((u >> 16) & 1u)) >> 16);
}
__device__ __forceinline__ float bf2f(ushort b) {
    return __uint_as_float((unsigned)b << 16);
}

// ---------------- fallback (round-1) atomic kernel ----------------
__global__ void lightgcn_scatter_atomic(const float* __restrict__ user_emb,
                                        const float* __restrict__ item_emb,
                                        const int* __restrict__ rows,
                                        const int* __restrict__ cols,
                                        const float* __restrict__ vals,
                                        float* __restrict__ user_out,
                                        float* __restrict__ item_out,
                                        int nnz) {
    const int lane   = threadIdx.x & 63;
    const int wave   = (blockIdx.x * blockDim.x + threadIdx.x) >> 6;
    const int nwaves = (gridDim.x * blockDim.x) >> 6;
    for (int e = wave; e < nnz; e += nwaves) {
        const int r = rows[e];
        const int c = cols[e];
        const float v = vals[e];
        atomicAdd(&user_out[(size_t)r * DIM + lane], v * item_emb[(size_t)c * DIM + lane]);
        atomicAdd(&item_out[(size_t)c * DIM + lane], v * user_emb[(size_t)r * DIM + lane]);
    }
}

// ---------------- bf16 table conversion (RNE), float4 vectorized -------------
__global__ void to_bf16(const float* __restrict__ a, int n, ushort* __restrict__ o) {
    const int nq = n >> 2;
    const float4* a4 = (const float4*)a;
    int i = blockIdx.x * blockDim.x + threadIdx.x;
    const int s = gridDim.x * blockDim.x;
    for (; i < nq; i += s) {
        const float4 f = a4[i];
        ushort4 u;
        u.x = f2bf(__float_as_uint(f.x));
        u.y = f2bf(__float_as_uint(f.y));
        u.z = f2bf(__float_as_uint(f.z));
        u.w = f2bf(__float_as_uint(f.w));
        *(ushort4*)(o + 4 * (size_t)i) = u;
    }
    for (int j = (nq << 2) + blockIdx.x * blockDim.x + threadIdx.x; j < n; j += s)
        o[j] = f2bf(__float_as_uint(a[j]));
}

// ---------------- init: cursor1[b] = b * span ----------------
__global__ void init_cursor(int* __restrict__ cursor1, int K1, int span) {
    const int b = blockIdx.x * blockDim.x + threadIdx.x;
    if (b < K1) cursor1[b] = b * span;
}

// ---------------- p1: block-local counting sort + destination-order write ----
__global__ __launch_bounds__(P1T)
void p1_kernel(const int* __restrict__ dest, const int* __restrict__ nbr,
               const float* __restrict__ vals, int nnz, int K1,
               int* __restrict__ cursor1,
               unsigned* __restrict__ meta1, ushort* __restrict__ val1) {
    __shared__ unsigned smeta[C1];     // 32 KiB (bucket-major staged meta)
    __shared__ ushort   sval[C1];      // 16 KiB
    __shared__ ushort   sbuck[C1];     // 16 KiB (bucket id per staged slot)
    __shared__ int      h[K1CAP * 4];  // 8 KiB  (x4-replicated histogram)
    __shared__ int      gd[K1CAP];     // global span base per bucket
    __shared__ int      lstart[K1CAP]; // local exclusive start per bucket
    __shared__ int      lc[K1CAP];     // cursors
    __shared__ int      ssum[P1T];     // block scan
    const int tid = threadIdx.x;
    const int e0 = blockIdx.x * C1;
    const int e1 = min(e0 + C1, nnz);
    const int n = e1 - e0;
    for (int t = tid; t < K1 * 4; t += P1T) h[t] = 0;
    __syncthreads();
    const int rr = tid & 3;

    int   dv[KP1];
    int   nv[KP1];
    float fv[KP1];
    #pragma unroll
    for (int k = 0; k < KP1; ++k) {
        const int i = tid + k * P1T;
        if (i < n) {
            dv[k] = dest[e0 + i];
            nv[k] = nbr[e0 + i];
            fv[k] = vals[e0 + i];
            atomicAdd(&h[((dv[k] >> L1BITS) << 2) | rr], 1);
        }
    }
    __syncthreads();

    int cb = 0;
    if (tid < K1) cb = h[tid*4] + h[tid*4+1] + h[tid*4+2] + h[tid*4+3];
    ssum[tid] = cb;
    __syncthreads();
    for (int off = 1; off < P1T; off <<= 1) {
        const int t = (tid >= off) ? ssum[tid - off] : 0;
        __syncthreads();
        ssum[tid] += t;
        __syncthreads();
    }
    if (tid < K1) {
        const int excl = ssum[tid] - cb;
        lstart[tid] = excl;
        lc[tid]     = excl;
        gd[tid]     = cb ? atomicAdd(&cursor1[tid], cb) : 0;
    }
    __syncthreads();

    #pragma unroll
    for (int k = 0; k < KP1; ++k) {
        const int i = tid + k * P1T;
        if (i < n) {
            const int b = dv[k] >> L1BITS;
            const int s = atomicAdd(&lc[b], 1);
            smeta[s] = ((unsigned)(dv[k] & (L1SZ - 1)) << SHIFT) | (unsigned)nv[k];
            sval[s]  = f2bf(__float_as_uint(fv[k]));
            sbuck[s] = (ushort)b;
        }
    }
    __syncthreads();

    // destination-order writeback: consecutive i -> consecutive dst in-run
    for (int i = tid; i < n; i += P1T) {
        const int b = sbuck[i];
        const int dst = gd[b] + (i - lstart[b]);
        meta1[dst] = smeta[i];
        val1[dst]  = sval[i];
    }
}

// ---------------- rowsort: local chunk sort, contiguous writes ----------------
__global__ __launch_bounds__(RSTH)
void rowsort_kernel(const unsigned* __restrict__ meta1,
                    const ushort* __restrict__ val1,
                    const int* __restrict__ cursor1, int span,
                    int CPB, int* __restrict__ rowptr, int* __restrict__ chunk_bad,
                    unsigned* __restrict__ meta2, ushort* __restrict__ val2) {
    __shared__ unsigned smeta[SCAP];   // 32 KiB
    __shared__ ushort   sval[SCAP];    // 16 KiB
    __shared__ int      ssum[L1SZ];
    __shared__ int      cur[L1SZ];
    __shared__ int      gbad;
    const int cid = blockIdx.x;
    const int B = cid / CPB, j = cid - B * CPB;
    const int tid = threadIdx.x;
    const int bst = B * span;
    const int nb  = cursor1[B] - bst;
    const int csz = (nb + CPB - 1) / CPB;
    const int s0 = min(bst + j * csz, bst + nb);
    const int s1 = min(s0 + csz, bst + nb);
    const int n = s1 - s0;
    int* rp = rowptr + (size_t)cid * (L1SZ + 1);

    if (n > CAPC) {   // far beyond sigma; correct slow fallback (acc filters)
        for (int i = tid; i < n; i += RSTH) {
            meta2[s0 + i] = meta1[s0 + i];
            val2[s0 + i]  = val1[s0 + i];
        }
        if (tid < L1SZ) rp[tid] = s0;
        if (tid == 0) { rp[L1SZ] = s1; chunk_bad[cid] = 1; }
        return;
    }

    if (tid < L1SZ) cur[tid] = 0;
    if (tid == 0) gbad = 0;
    __syncthreads();

    unsigned mv[KMAX];
    ushort   vv[KMAX];
    #pragma unroll
    for (int k = 0; k < KMAX; ++k) {
        const int i = tid + k * RSTH;
        if (i < n) {
            mv[k] = __builtin_nontemporal_load(&meta1[s0 + i]);
            vv[k] = __builtin_nontemporal_load(&val1[s0 + i]);
            atomicAdd(&cur[mv[k] >> SHIFT], 1);
        }
    }
    __syncthreads();
    if (tid < L1SZ) ssum[tid] = cur[tid];
    __syncthreads();
    for (int off = 1; off < L1SZ; off <<= 1) {
        int t = 0;
        if (tid < L1SZ && tid >= off) t = ssum[tid - off];
        __syncthreads();
        if (tid < L1SZ) ssum[tid] += t;
        __syncthreads();
    }
    if (tid < L1SZ) {
        const int excl = tid ? ssum[tid - 1] : 0;
        rp[tid] = s0 + excl;
        cur[tid] = excl;
    }
    if (tid == 0) rp[L1SZ] = s1;
    if (tid < GROUPS) {
        const int gs = tid ? ssum[tid * GRS - 1] : 0;
        if (ssum[(tid + 1) * GRS - 1] - gs > SCAP) gbad = 1;
    }
    __syncthreads();

    if (gbad) {   // stage overflow (way out on the tail); correct fallback
        #pragma unroll
        for (int k = 0; k < KMAX; ++k) {
            const int i = tid + k * RSTH;
            if (i < n) { meta2[s0 + i] = mv[k]; val2[s0 + i] = vv[k]; }
        }
        if (tid == 0) chunk_bad[cid] = 1;
        return;
    }
    if (tid == 0) chunk_bad[cid] = 0;

    for (int g = 0; g < GROUPS; ++g) {
        const int gs = g ? ssum[g * GRS - 1] : 0;
        const int ge = ssum[(g + 1) * GRS - 1];
        #pragma unroll
        for (int k = 0; k < KMAX; ++k) {
            const int i = tid + k * RSTH;
            if (i < n) {
                const int row = (int)(mv[k] >> SHIFT);
                if ((row >> 7) == g) {               // GRS = 128
                    const int slot = atomicAdd(&cur[row], 1);
                    smeta[slot - gs] = mv[k];
                    sval[slot - gs]  = vv[k];
                }
            }
        }
        __syncthreads();
        for (int i = tid; i < ge - gs; i += RSTH) {
            meta2[s0 + gs + i] = smeta[i];
            val2[s0 + gs + i]  = sval[i];
        }
        __syncthreads();
    }
}

// ---------------- acc: wave/row, hoisted bounds, eighth-wave ushort8 ---------
template<int CPBT>
__global__ __launch_bounds__(256)
void acc_kernel(const ushort* __restrict__ tbl,
                const unsigned* __restrict__ meta2,
                const ushort* __restrict__ val2,
                const int* __restrict__ rowptr,
                const int* __restrict__ chunk_bad,
                int nrows, float* __restrict__ out) {
    const int lane = threadIdx.x & 63;
    const int oc  = lane >> 3;    // eighth handles edge e+oc
    const int li  = lane & 7;     // dims 8*li .. 8*li+7
    const int r = (int)((blockIdx.x * blockDim.x + threadIdx.x) >> 6);
    const int B = r >> L1BITS;
    const int rlow = r & (L1SZ - 1);
    int stj[CPBT], enj[CPBT], cbj[CPBT];
    #pragma unroll
    for (int j = 0; j < CPBT; ++j) {
        const int cid = B * CPBT + j;
        const int* rp = rowptr + (size_t)cid * (L1SZ + 1);
        cbj[j] = chunk_bad[cid];
        stj[j] = rp[rlow];
        enj[j] = rp[rlow + 1];
    }
    float a0 = 0.f, a1 = 0.f, a2 = 0.f, a3 = 0.f;
    float a4 = 0.f, a5 = 0.f, a6 = 0.f, a7 = 0.f;
    #define STEP(EI) { const unsigned m_ = meta2[EI];                          \
        const float v_ = bf2f(val2[EI]);                                       \
        const us8 g_ = *(const us8*)(tbl + (size_t)(m_ & NMASK) * DIM + 8*li); \
        a0 = fmaf(v_, bf2f(g_[0]), a0); a1 = fmaf(v_, bf2f(g_[1]), a1);        \
        a2 = fmaf(v_, bf2f(g_[2]), a2); a3 = fmaf(v_, bf2f(g_[3]), a3);        \
        a4 = fmaf(v_, bf2f(g_[4]), a4); a5 = fmaf(v_, bf2f(g_[5]), a5);        \
        a6 = fmaf(v_, bf2f(g_[6]), a6); a7 = fmaf(v_, bf2f(g_[7]), a7); }
    #pragma unroll
    for (int j = 0; j < CPBT; ++j) {
        if (__builtin_expect(cbj[j] != 0, 0)) {
            const int cid = B * CPBT + j;
            const int* rp = rowptr + (size_t)cid * (L1SZ + 1);
            const int cs = rp[0], ce = rp[L1SZ];
            for (int e = cs; e < ce; e += 8) {
                if (e + oc < ce) {
                    const unsigned m_ = meta2[e + oc];
                    if ((int)(m_ >> SHIFT) == rlow) {
                        const float v_ = bf2f(val2[e + oc]);
                        const us8 g_ = *(const us8*)(tbl + (size_t)(m_ & NMASK) * DIM + 8*li);
                        a0 = fmaf(v_, bf2f(g_[0]), a0); a1 = fmaf(v_, bf2f(g_[1]), a1);
                        a2 = fmaf(v_, bf2f(g_[2]), a2); a3 = fmaf(v_, bf2f(g_[3]), a3);
                        a4 = fmaf(v_, bf2f(g_[4]), a4); a5 = fmaf(v_, bf2f(g_[5]), a5);
                        a6 = fmaf(v_, bf2f(g_[6]), a6); a7 = fmaf(v_, bf2f(g_[7]), a7);
                    }
                }
            }
        } else {
            const int en = enj[j];
            int e = stj[j];
            for (; e + 16 <= en; e += 16) { STEP(e + oc); STEP(e + 8 + oc); }
            if (e + 8 <= en) { STEP(e + oc); e += 8; }
            if (e + oc < en) STEP(e + oc);
        }
    }
    #undef STEP
    a0 += __shfl_xor(a0, 8); a0 += __shfl_xor(a0, 16); a0 += __shfl_xor(a0, 32);
    a1 += __shfl_xor(a1, 8); a1 += __shfl_xor(a1, 16); a1 += __shfl_xor(a1, 32);
    a2 += __shfl_xor(a2, 8); a2 += __shfl_xor(a2, 16); a2 += __shfl_xor(a2, 32);
    a3 += __shfl_xor(a3, 8); a3 += __shfl_xor(a3, 16); a3 += __shfl_xor(a3, 32);
    a4 += __shfl_xor(a4, 8); a4 += __shfl_xor(a4, 16); a4 += __shfl_xor(a4, 32);
    a5 += __shfl_xor(a5, 8); a5 += __shfl_xor(a5, 16); a5 += __shfl_xor(a5, 32);
    a6 += __shfl_xor(a6, 8); a6 += __shfl_xor(a6, 16); a6 += __shfl_xor(a6, 32);
    a7 += __shfl_xor(a7, 8); a7 += __shfl_xor(a7, 16); a7 += __shfl_xor(a7, 32);
    if (lane < 8 && r < nrows) {
        float* op = out + (size_t)r * DIM + 8*li;
        *(float4*)(op)     = make_float4(a0, a1, a2, a3);
        *(float4*)(op + 4) = make_float4(a4, a5, a6, a7);
    }
}

extern "C" void kernel_launch(void* const* d_in, const int* in_sizes, int n_in,
                              void* d_out, int out_size, void* d_ws, size_t ws_size,
                              hipStream_t stream) {
    const float* user_emb = (const float*)d_in[0];
    const float* item_emb = (const float*)d_in[1];
    const int*   rows     = (const int*)d_in[2];
    const int*   cols     = (const int*)d_in[3];
    const float* vals     = (const float*)d_in[4];

    const int nnz     = in_sizes[2];
    const int n_users = in_sizes[0] / DIM;
    const int n_items = in_sizes[1] / DIM;

    float* user_out = (float*)d_out;
    float* item_out = (float*)d_out + (size_t)in_sizes[0];

    // ---- per-side bucket geometry (fixed padded spans) ----
    const int K1_i = (n_items + L1SZ - 1) >> L1BITS;
    const int K1_u = (n_users + L1SZ - 1) >> L1BITS;
    auto span_for = [&](int K1) {
        const double mean = (double)nnz / (double)K1;
        int sp = (int)(mean + 16.0 * __builtin_sqrt(mean) + 256.0);
        return (sp + 63) & ~63;
    };
    const int span_i = span_for(K1_i);
    const int span_u = span_for(K1_u);
    const size_t P_i = (size_t)K1_i * span_i;
    const size_t P_u = (size_t)K1_u * span_u;
    const size_t P = (P_i > P_u ? P_i : P_u) + 65536;   // + overflow tail

    // ---- workspace layout ----
    size_t oi = 0;
    const size_t cursor1_o  = oi; oi += K1CAP;
    const size_t cbad_o     = oi; oi += (size_t)K1CAP * CPBMAX;
    const size_t rowptr_o   = oi; oi += (size_t)K1CAP * CPBMAX * (L1SZ + 1);
    const size_t meta_bytes = oi * sizeof(int);
    const size_t tbl_off     = (meta_bytes + 255) & ~(size_t)255;
    const size_t tblu_bytes  = (size_t)n_users * DIM * sizeof(ushort);
    const size_t tbli_bytes  = (size_t)n_items * DIM * sizeof(ushort);
    const size_t meta1_off   = (tbl_off + tblu_bytes + tbli_bytes + 255) & ~(size_t)255;
    const size_t val1_off    = meta1_off + ((P * 4 + 255) & ~(size_t)255);
    const size_t meta2_off   = val1_off + ((P * 2 + 255) & ~(size_t)255);
    const size_t val2_off    = meta2_off + ((P * 4 + 255) & ~(size_t)255);
    const size_t need        = val2_off + P * sizeof(ushort);

    if (n_users > (1 << SHIFT) || n_items > (1 << SHIFT) ||
        n_users > K1CAP * L1SZ || n_items > K1CAP * L1SZ || ws_size < need) {
        hipMemsetAsync(d_out, 0, (size_t)out_size * sizeof(float), stream);
        lightgcn_scatter_atomic<<<2048, 256, 0, stream>>>(user_emb, item_emb, rows,
                                                          cols, vals, user_out,
                                                          item_out, nnz);
        return;
    }

    int* wsi       = (int*)d_ws;
    int* cursor1   = wsi + cursor1_o;
    int* chunk_bad = wsi + cbad_o;
    int* rowptr    = wsi + rowptr_o;
    ushort* tblu   = (ushort*)((char*)d_ws + tbl_off);
    ushort* tbli   = tblu + (size_t)n_users * DIM;
    unsigned* meta1 = (unsigned*)((char*)d_ws + meta1_off);
    ushort*   val1  = (ushort*)((char*)d_ws + val1_off);
    unsigned* meta2 = (unsigned*)((char*)d_ws + meta2_off);
    ushort*   val2  = (ushort*)((char*)d_ws + val2_off);

    to_bf16<<<1024, 256, 0, stream>>>(user_emb, n_users * DIM, tblu);
    to_bf16<<<1024, 256, 0, stream>>>(item_emb, n_items * DIM, tbli);

    const int p1_grid = (nnz + C1 - 1) / C1;

    struct Side { const int* dest; const int* nbr; int nrows; int K1; int span;
                  const ushort* tbl; float* out; };
    const Side sides[2] = {
        { cols, rows, n_items, K1_i, span_i, tblu, item_out },  // item side gathers USER rows
        { rows, cols, n_users, K1_u, span_u, tbli, user_out },  // user side gathers ITEM rows
    };

    for (int s = 0; s < 2; ++s) {
        const Side& S = sides[s];
        const long long meanb = (long long)nnz / S.K1;
        int CPB = (int)((meanb + 12287) / 12288);
        if (CPB < 1) CPB = 1;
        if (CPB > CPBMAX) CPB = CPBMAX;
        init_cursor<<<(S.K1 + 255) / 256, 256, 0, stream>>>(cursor1, S.K1, S.span);
        p1_kernel<<<p1_grid, P1T, 0, stream>>>(S.dest, S.nbr, vals, nnz, S.K1,
                                               cursor1, meta1, val1);
        rowsort_kernel<<<S.K1 * CPB, RSTH, 0, stream>>>(meta1, val1, cursor1, S.span,
                                                        CPB, rowptr, chunk_bad,
                                                        meta2, val2);
        const int acc_grid = S.K1 * (L1SZ / 4);   // 4 rows (waves) per block
        switch (CPB) {
            case 1: acc_kernel<1><<<acc_grid, 256, 0, stream>>>(S.tbl, meta2, val2, rowptr, chunk_bad, S.nrows, S.out); break;
            case 2: acc_kernel<2><<<acc_grid, 256, 0, stream>>>(S.tbl, meta2, val2, rowptr, chunk_bad, S.nrows, S.out); break;
            case 3: acc_kernel<3><<<acc_grid, 256, 0, stream>>>(S.tbl, meta2, val2, rowptr, chunk_bad, S.nrows, S.out); break;
            case 4: acc_kernel<4><<<acc_grid, 256, 0, stream>>>(S.tbl, meta2, val2, rowptr, chunk_bad, S.nrows, S.out); break;
            case 5: acc_kernel<5><<<acc_grid, 256, 0, stream>>>(S.tbl, meta2, val2, rowptr, chunk_bad, S.nrows, S.out); break;
            case 6: acc_kernel<6><<<acc_grid, 256, 0, stream>>>(S.tbl, meta2, val2, rowptr, chunk_bad, S.nrows, S.out); break;
            case 7: acc_kernel<7><<<acc_grid, 256, 0, stream>>>(S.tbl, meta2, val2, rowptr, chunk_bad, S.nrows, S.out); break;
            default: acc_kernel<8><<<acc_grid, 256, 0, stream>>>(S.tbl, meta2, val2, rowptr, chunk_bad, S.nrows, S.out); break;
        }
    }
}